// Round 18
// baseline (403.610 us; speedup 1.0000x reference)
//
#include <hip/hip_runtime.h>
#include <stdint.h>

// ---------------------------------------------------------------------------
// CrossAttentionRope: x(16,256,768), ctx(16,4096,768) f32 -> out(16,256,768) f32
// R18: kv8 inner loop re-batched (derived to closure from R17's ledger):
//      per tile: vmcnt(4) -> barrier -> read ALL 48 fragment ds_reads
//      (both A halves + both B halves) -> lgkmcnt(0)+sched_barrier ->
//      barrier -> issue 4 stages (T+1 bots, T+2 tops) -> 64-MFMA setprio
//      cluster. 2 barriers/tile (was 4), one LDS drain (was 4).
//      Slot safety: dbuf reads all complete before barrier2, so T+2-top
//      staging into dbuf is race-free; T+1-bot targets dbuf^1 (readers
//      retired last tile). Ledger: uniform vmcnt(4), vmcnt(0) at T=11.
//      All formulas/epilogues verbatim R17. cvt/twt/Q/O/attn verbatim R17.
// ---------------------------------------------------------------------------

typedef __bf16 bf16x8 __attribute__((ext_vector_type(8)));
typedef unsigned short u16x8 __attribute__((ext_vector_type(8)));
typedef unsigned short u16x4 __attribute__((ext_vector_type(4)));
typedef uint32_t u32x4 __attribute__((ext_vector_type(4)));
typedef float f32x4 __attribute__((ext_vector_type(4)));

#define DIMF 768
#define NHEAD 12
#define NKV 4096
#define NQ 256
#define NB 16

struct alignas(8) us4 { unsigned short x, y, z, w; };

__device__ __forceinline__ unsigned short f2bf(float x) {
  uint32_t u = __float_as_uint(x);
  u += 0x7fffu + ((u >> 16) & 1u);   // round-to-nearest-even
  return (unsigned short)(u >> 16);
}

__device__ __forceinline__ uint32_t cvtpk(float a, float b) {
  uint32_t r;
  asm("v_cvt_pk_bf16_f32 %0, %1, %2" : "=v"(r) : "v"(a), "v"(b));
  return r;
}

__device__ __forceinline__ void gld_lds16(const unsigned short* g, unsigned short* l) {
  __builtin_amdgcn_global_load_lds(
      (const __attribute__((address_space(1))) uint32_t*)(uintptr_t)g,
      (__attribute__((address_space(3))) uint32_t*)(uintptr_t)l, 16, 0, 0);
}

// ---------------- convert f32 -> bf16 (vectorized, grid-stride) ------------
__global__ void cvt_kernel(const float* __restrict__ in, unsigned short* __restrict__ out, int n) {
  int stride = gridDim.x * blockDim.x * 4;
  for (int i = (blockIdx.x * blockDim.x + threadIdx.x) * 4; i < n; i += stride) {
    float4 v = *(const float4*)(in + i);
    us4 o{f2bf(v.x), f2bf(v.y), f2bf(v.z), f2bf(v.w)};
    *(us4*)(out + i) = o;
  }
}

// ---------------- weight transpose + cvt: Wt[n][k] = W[k][n] ---------------
__global__ void twt_kernel(const float* __restrict__ W0, const float* __restrict__ W1,
                           const float* __restrict__ W2, const float* __restrict__ W3,
                           unsigned short* __restrict__ O0, unsigned short* __restrict__ O1,
                           unsigned short* __restrict__ O2, unsigned short* __restrict__ O3) {
  const float* W; unsigned short* O;
  switch (blockIdx.z) {
    case 0: W = W0; O = O0; break;
    case 1: W = W1; O = O1; break;
    case 2: W = W2; O = O2; break;
    default: W = W3; O = O3; break;
  }
  __shared__ float t[32][33];
  int x0 = blockIdx.x * 32, y0 = blockIdx.y * 32;
  int tx = threadIdx.x, ty = threadIdx.y;
#pragma unroll
  for (int j = 0; j < 4; ++j)
    t[ty + 8 * j][tx] = W[(size_t)(y0 + ty + 8 * j) * DIMF + x0 + tx];
  __syncthreads();
#pragma unroll
  for (int j = 0; j < 4; ++j)
    O[(size_t)(x0 + ty + 8 * j) * DIMF + y0 + tx] = f2bf(t[tx][ty + 8 * j]);
}

// ---------------- merged KV GEMM: 256x256, tile-batched pipeline ------------
// C(256x256 of 65536x1536) = ctxb * wkvt^T. Grid 1536 (256 rows x 6 cols),
// col-fast XCD swizzle. 512 thr / 8 waves; per-wave C = 128x64 interleaved.
__launch_bounds__(512, 1)
__global__ void kv8_kernel(const unsigned short* __restrict__ A,
                           const unsigned short* __restrict__ Bkv,
                           unsigned short* __restrict__ Ko,
                           unsigned short* __restrict__ Vt,
                           const float* __restrict__ rope) {
  extern __shared__ unsigned short smem[];   // 65536 shorts = 128KB
  const int t = threadIdx.x;
  const int lane = t & 63, wid = t >> 6;
  const int g = lane >> 4, lc = lane & 15;
  const int wr = wid >> 2, wc = wid & 3;

  const int swz = (blockIdx.x & 7) * 192 + (blockIdx.x >> 3);  // 1536%8==0
  const int rowBase = (swz / 6) * 256;
  const int colBase = (swz % 6) * 256;

  f32x4 acc[8][4];
#pragma unroll
  for (int m = 0; m < 8; ++m)
#pragma unroll
    for (int n = 0; n < 4; ++n)
#pragma unroll
      for (int r = 0; r < 4; ++r) acc[m][n][r] = 0.f;

  // staging map (R11-proven): lane -> row l>>3 within 8-row group; source
  // chunk pre-XOR'd so LDS[row][slot s] holds global chunk s^(row&7).
  const int sr = lane >> 3;
  const int sc = (lane & 7) ^ sr;
  const unsigned short* Abase0 = A + (size_t)(rowBase + wid * 16 + sr) * DIMF + sc * 8;
  const unsigned short* Bbase0 = Bkv + (size_t)(colBase + wid * 16 + sr) * DIMF + sc * 8;

#define STAGE_A(T, h)                                                              \
  do {                                                                             \
    unsigned short* _lb = smem + (((T) & 1) * 2 + (h)) * 8192;                     \
    const unsigned short* _gb = Abase0 + (size_t)(h) * 128 * DIMF + (T) * 64;      \
    gld_lds16(_gb, _lb + (wid * 16) * 64);                                         \
    gld_lds16(_gb + (size_t)8 * DIMF, _lb + (wid * 16 + 8) * 64);                  \
  } while (0)
#define STAGE_B(T, h)                                                              \
  do {                                                                             \
    unsigned short* _lb = smem + 32768 + (((T) & 1) * 2 + (h)) * 8192;             \
    const unsigned short* _gb = Bbase0 + (size_t)(h) * 128 * DIMF + (T) * 64;      \
    gld_lds16(_gb, _lb + (wid * 16) * 64);                                         \
    gld_lds16(_gb + (size_t)8 * DIMF, _lb + (wid * 16 + 8) * 64);                  \
  } while (0)

  // prologue: T0 complete + T1 tops (issue order defines the vmcnt ledger)
  STAGE_A(0, 0); STAGE_B(0, 0); STAGE_A(0, 1); STAGE_B(0, 1);
  STAGE_A(1, 0); STAGE_B(1, 0);

  bf16x8 af[2][4][2], bfr[2][2][2];

  for (int T = 0; T < 12; ++T) {
    const int dbuf = T & 1;
    // ledger: need T's 4 halves (8 loads); T+1 tops (4) stay in flight
    if (T == 11) asm volatile("s_waitcnt vmcnt(0)" ::: "memory");
    else         asm volatile("s_waitcnt vmcnt(4)" ::: "memory");
    asm volatile("" ::: "memory");
    __builtin_amdgcn_s_barrier();     // all waves' tile-T loads visible
    asm volatile("" ::: "memory");

    // read ALL fragments for tile T (both A halves, both B halves)
#pragma unroll
    for (int ah = 0; ah < 2; ++ah) {
      const unsigned short* Ab = smem + (dbuf * 2 + ah) * 8192;
#pragma unroll
      for (int mp = 0; mp < 4; ++mp)
#pragma unroll
        for (int kk = 0; kk < 2; ++kk) {
          int row = mp * 32 + wr * 16 + lc;
          af[ah][mp][kk] = *(const bf16x8*)&Ab[row * 64 + (((kk * 4 + g) ^ (row & 7)) << 3)];
        }
    }
#pragma unroll
    for (int bh = 0; bh < 2; ++bh) {
      const unsigned short* Bb = smem + 32768 + (dbuf * 2 + bh) * 8192;
#pragma unroll
      for (int np = 0; np < 2; ++np)
#pragma unroll
        for (int kk = 0; kk < 2; ++kk) {
          int row = np * 64 + wc * 16 + lc;
          bfr[bh][np][kk] = *(const bf16x8*)&Bb[row * 64 + (((kk * 4 + g) ^ (row & 7)) << 3)];
        }
    }
    asm volatile("s_waitcnt lgkmcnt(0)" ::: "memory");
    __builtin_amdgcn_sched_barrier(0);   // rule #18
    asm volatile("" ::: "memory");
    __builtin_amdgcn_s_barrier();        // all waves done reading dbuf slots
    // stage next tiles (slots' readers all retired at barrier above)
    if (T + 1 < 12) { STAGE_B(T + 1, 1); STAGE_A(T + 1, 1); }
    if (T + 2 < 12) { STAGE_A(T + 2, 0); STAGE_B(T + 2, 0); }
    asm volatile("" ::: "memory");

    __builtin_amdgcn_s_setprio(1);
#pragma unroll
    for (int ah = 0; ah < 2; ++ah)
#pragma unroll
      for (int bh = 0; bh < 2; ++bh)
#pragma unroll
        for (int mp = 0; mp < 4; ++mp)
#pragma unroll
          for (int np = 0; np < 2; ++np)
#pragma unroll
            for (int kk = 0; kk < 2; ++kk)
              acc[4 * ah + mp][2 * bh + np] = __builtin_amdgcn_mfma_f32_16x16x32_bf16(
                  af[ah][mp][kk], bfr[bh][np][kk], acc[4 * ah + mp][2 * bh + np], 0, 0, 0);
    __builtin_amdgcn_s_setprio(0);
  }
#undef STAGE_A
#undef STAGE_B

  // ---- epilogue (C/D: col=lc, row=g*4+r — proven); block-uniform branch ----
  if (colBase < 768) {   // K output + rope
#pragma unroll
    for (int m = 0; m < 8; ++m)
#pragma unroll
      for (int n = 0; n < 4; ++n)
#pragma unroll
        for (int r = 0; r < 4; ++r) {
          int p = rowBase + m * 32 + wr * 16 + g * 4 + r;
          int f = colBase + n * 64 + wc * 16 + lc;
          int d = f & 63, h = f >> 6;
          float v = acc[m][n][r];
          float vo = __shfl_xor(v, 1);
          int b = p >> 12, nkv = p & 4095;
          float sn = rope[nkv * 128 + d], cs = rope[nkv * 128 + 64 + d];
          float o = (d & 1) ? fmaf(vo, sn, v * cs) : fmaf(-vo, sn, v * cs);
          Ko[((size_t)(b * NHEAD + h) * NKV + nkv) * 64 + d] = f2bf(o);
        }
  } else {               // V output, transposed [b][h][d][nkv]
#pragma unroll
    for (int m = 0; m < 8; ++m)
#pragma unroll
      for (int n = 0; n < 4; ++n) {
        int p0 = rowBase + m * 32 + wr * 16 + g * 4;
        int b = p0 >> 12, nkv0 = p0 & 4095;
        int f = (colBase - 768) + n * 64 + wc * 16 + lc;
        int d = f & 63, h = f >> 6;
        us4 wv{f2bf(acc[m][n][0]), f2bf(acc[m][n][1]), f2bf(acc[m][n][2]), f2bf(acc[m][n][3])};
        *(us4*)&Vt[((size_t)(b * NHEAD + h) * 64 + d) * NKV + nkv0] = wv;
      }
  }
}

// ---------------- GEMM (R5/R8-proven reg-staged): Q-proj / O-proj -----------
// MODE 2: Q-proj (+rope_q, *0.125) -> Q [b][h][nq][64] bf16  [2D grid]
// MODE 3: O-proj -> out f32 [p][768]                          [2D grid]
template <int MODE>
__launch_bounds__(256, 2)
__global__ void gemm_kernel(const unsigned short* __restrict__ A,
                            const unsigned short* __restrict__ Bt,
                            void* __restrict__ outp,
                            const float* __restrict__ rope) {
  __shared__ unsigned short As[128 * 64];
  __shared__ unsigned short Bs[128 * 64];
  const int t = threadIdx.x;
  const int lane = t & 63, wid = t >> 6;
  const int g = lane >> 4, lc = lane & 15;
  const int wr = wid >> 1, wc = wid & 1;
  const int rowBase = blockIdx.x * 128, colBase = blockIdx.y * 128;

  const f32x4 z4 = {0.f, 0.f, 0.f, 0.f};
  f32x4 acc[4][4];
#pragma unroll
  for (int m = 0; m < 4; ++m)
#pragma unroll
    for (int n = 0; n < 4; ++n) acc[m][n] = z4;

  const int r0 = t >> 3;
  const int c0 = t & 7;

  bf16x8 ra[4], rbx[4];
#pragma unroll
  for (int pp = 0; pp < 4; ++pp) {
    int row = pp * 32 + r0;
    ra[pp] = *(const bf16x8*)(A + (size_t)(rowBase + row) * DIMF + c0 * 8);
    rbx[pp] = *(const bf16x8*)(Bt + (size_t)(colBase + row) * DIMF + c0 * 8);
  }

  for (int kb = 0; kb < 12; ++kb) {
    __syncthreads();
#pragma unroll
    for (int pp = 0; pp < 4; ++pp) {
      int row = pp * 32 + r0;
      int ph = ((c0 ^ (row & 7)) << 3);
      *(bf16x8*)&As[row * 64 + ph] = ra[pp];
      *(bf16x8*)&Bs[row * 64 + ph] = rbx[pp];
    }
    __syncthreads();
    if (kb + 1 < 12) {
      int kn = (kb + 1) * 64;
#pragma unroll
      for (int pp = 0; pp < 4; ++pp) {
        int row = pp * 32 + r0;
        ra[pp] = *(const bf16x8*)(A + (size_t)(rowBase + row) * DIMF + kn + c0 * 8);
        rbx[pp] = *(const bf16x8*)(Bt + (size_t)(colBase + row) * DIMF + kn + c0 * 8);
      }
    }
#pragma unroll
    for (int kk = 0; kk < 2; ++kk) {
      bf16x8 af[4], bfr[4];
#pragma unroll
      for (int m = 0; m < 4; ++m) {
        int row = wr * 64 + m * 16 + lc;
        int ch = kk * 4 + g;
        af[m] = *(const bf16x8*)&As[row * 64 + (((ch ^ (row & 7))) << 3)];
      }
#pragma unroll
      for (int n = 0; n < 4; ++n) {
        int row = wc * 64 + n * 16 + lc;
        int ch = kk * 4 + g;
        bfr[n] = *(const bf16x8*)&Bs[row * 64 + (((ch ^ (row & 7))) << 3)];
      }
#pragma unroll
      for (int m = 0; m < 4; ++m)
#pragma unroll
        for (int n = 0; n < 4; ++n)
          acc[m][n] = __builtin_amdgcn_mfma_f32_16x16x32_bf16(af[m], bfr[n], acc[m][n], 0, 0, 0);
    }
  }

  if (MODE == 2) {
    unsigned short* Ko = (unsigned short*)outp;
#pragma unroll
    for (int m = 0; m < 4; ++m)
#pragma unroll
      for (int n = 0; n < 4; ++n)
#pragma unroll
        for (int r = 0; r < 4; ++r) {
          int p = rowBase + wr * 64 + m * 16 + g * 4 + r;
          int f = colBase + wc * 64 + n * 16 + lc;
          int d = f & 63, h = f >> 6;
          float v = acc[m][n][r];
          float vo = __shfl_xor(v, 1);
          int b = p >> 8, nq = p & 255;
          float sn = rope[nq * 128 + d], cs = rope[nq * 128 + 64 + d];
          float o = (d & 1) ? fmaf(vo, sn, v * cs) : fmaf(-vo, sn, v * cs);
          Ko[((size_t)(b * NHEAD + h) * NQ + nq) * 64 + d] = f2bf(o * 0.125f);
        }
  } else {
    float* Co = (float*)outp;
#pragma unroll
    for (int m = 0; m < 4; ++m)
#pragma unroll
      for (int n = 0; n < 4; ++n)
#pragma unroll
        for (int r = 0; r < 4; ++r) {
          int p = rowBase + wr * 64 + m * 16 + g * 4 + r;
          int f = colBase + wc * 64 + n * 16 + lc;
          Co[(size_t)p * DIMF + f] = acc[m][n][r];
        }
  }
}

// ---------------- flash attention (R5-proven, verbatim) --------------------
__launch_bounds__(256, 2)
__global__ void attn_kernel(const unsigned short* __restrict__ Qb,
                            const unsigned short* __restrict__ Kb,
                            const unsigned short* __restrict__ Vtb,
                            unsigned short* __restrict__ Ob) {
  __shared__ unsigned short Ks[128 * 64];    // [kv][d]  16KB, chunk ^= (kv&7)
  __shared__ unsigned short Vts[64 * 128];   // [d][kv'] 16KB, chunk ^= (d&15)
  const int logical = (blockIdx.x & 7) * 96 + (blockIdx.x >> 3);  // 768%8==0
  const int qt = logical & 3, bh = logical >> 2;
  const int b = bh / NHEAD, h = bh % NHEAD;
  const int t = threadIdx.x;
  const int lane = t & 63, w = t >> 6;
  const int g = lane >> 4, lc = lane & 15;
  const int qrow = qt * 64 + w * 16 + lc;

  bf16x8 qf[2];
#pragma unroll
  for (int kk = 0; kk < 2; ++kk)
    qf[kk] = *(const bf16x8*)(Qb + ((size_t)bh * NQ + qrow) * 64 + kk * 32 + g * 8);

  const f32x4 z4 = {0.f, 0.f, 0.f, 0.f};
  f32x4 oacc[4];
#pragma unroll
  for (int df = 0; df < 4; ++df) oacc[df] = z4;
  float mrun = -1e30f, lrun = 0.f;

  const int r0 = t >> 3, c0 = t & 7;
  const int d0 = t >> 4, cv = t & 15;
  const int pbase = 32 * (cv >> 2) + 16 * (cv & 1) + 4 * ((cv >> 1) & 1);
  const int ch0 = pbase >> 3, of0 = pbase & 7;
  const int ch1 = (pbase + 8) >> 3;

  u16x8 rk[4], rv[4];
#define LOAD_TILE(KT)                                                                        \
  do {                                                                                       \
    const int kvb = (KT) * 128;                                                              \
    _Pragma("unroll")                                                                        \
    for (int pp = 0; pp < 4; ++pp)                                                           \
      rk[pp] = *(const u16x8*)(Kb + ((size_t)bh * NKV + kvb + pp * 32 + r0) * 64 + c0 * 8);  \
    _Pragma("unroll")                                                                        \
    for (int pp = 0; pp < 4; ++pp)                                                           \
      rv[pp] = *(const u16x8*)(Vtb + ((size_t)bh * 64 + pp * 16 + d0) * NKV + kvb + cv * 8); \
  } while (0)

  LOAD_TILE(0);

  for (int kt = 0; kt < 32; ++kt) {
    __syncthreads();
#pragma unroll
    for (int pp = 0; pp < 4; ++pp) {
      int row = pp * 32 + r0;
      *(u16x8*)&Ks[row * 64 + ((c0 ^ (row & 7)) << 3)] = rk[pp];
    }
#pragma unroll
    for (int pp = 0; pp < 4; ++pp) {
      int d = pp * 16 + d0;
      u16x4 lo = __builtin_shufflevector(rv[pp], rv[pp], 0, 1, 2, 3);
      u16x4 hi = __builtin_shufflevector(rv[pp], rv[pp], 4, 5, 6, 7);
      *(u16x4*)&Vts[d * 128 + ((ch0 ^ (d & 15)) << 3) + of0] = lo;
      *(u16x4*)&Vts[d * 128 + ((ch1 ^ (d & 15)) << 3) + of0] = hi;
    }
    if (kt + 1 < 32) LOAD_TILE(kt + 1);
    __syncthreads();

    f32x4 s[8];
#pragma unroll
    for (int c = 0; c < 8; ++c) s[c] = z4;
#pragma unroll
    for (int kk = 0; kk < 2; ++kk)
#pragma unroll
      for (int c = 0; c < 8; ++c) {
        int row = c * 16 + lc;
        bf16x8 kf = *(const bf16x8*)&Ks[row * 64 + (((kk * 4 + g) ^ (row & 7)) << 3)];
        s[c] = __builtin_amdgcn_mfma_f32_16x16x32_bf16(kf, qf[kk], s[c], 0, 0, 0);
      }

    float mx = s[0][0];
#pragma unroll
    for (int c = 0; c < 8; ++c)
#pragma unroll
      for (int r = 0; r < 4; ++r) mx = fmaxf(mx, s[c][r]);
    mx = fmaxf(mx, __shfl_xor(mx, 16));
    mx = fmaxf(mx, __shfl_xor(mx, 32));
    float nm = fmaxf(mrun, mx);
    float al = __expf(mrun - nm);
    mrun = nm;
    float ls = 0.f;
#pragma unroll
    for (int c = 0; c < 8; ++c)
#pragma unroll
      for (int r = 0; r < 4; ++r) {
        float p = __expf(s[c][r] - nm);
        s[c][r] = p;
        ls += p;
      }
    ls += __shfl_xor(ls, 16);
    ls += __shfl_xor(ls, 32);
    lrun = lrun * al + ls;
#pragma unroll
    for (int df = 0; df < 4; ++df)
#pragma unroll
      for (int r = 0; r < 4; ++r) oacc[df][r] *= al;

    uint32_t pk[8][2];
#pragma unroll
    for (int c = 0; c < 8; ++c)
#pragma unroll
      for (int w2 = 0; w2 < 2; ++w2)
        pk[c][w2] = cvtpk(s[c][2 * w2], s[c][2 * w2 + 1]);

#pragma unroll
    for (int kb = 0; kb < 4; ++kb) {
      u32x4 pw = {pk[2 * kb][0], pk[2 * kb][1], pk[2 * kb + 1][0], pk[2 * kb + 1][1]};
      bf16x8 pa = __builtin_bit_cast(bf16x8, pw);
#pragma unroll
      for (int df = 0; df < 4; ++df) {
        int row = df * 16 + lc;
        bf16x8 vf = *(const bf16x8*)&Vts[row * 128 + (((kb * 4 + g) ^ (row & 15)) << 3)];
        oacc[df] = __builtin_amdgcn_mfma_f32_16x16x32_bf16(vf, pa, oacc[df], 0, 0, 0);
      }
    }
  }
#undef LOAD_TILE

  float inv = 1.0f / lrun;
#pragma unroll
  for (int df = 0; df < 4; ++df) {
    us4 wv{f2bf(oacc[df][0] * inv), f2bf(oacc[df][1] * inv),
           f2bf(oacc[df][2] * inv), f2bf(oacc[df][3] * inv)};
    *(us4*)&Ob[((size_t)b * NQ + qrow) * DIMF + h * 64 + df * 16 + g * 4] = wv;
  }
}

// ---------------- launch ----------------------------------------------------
extern "C" void kernel_launch(void* const* d_in, const int* in_sizes, int n_in,
                              void* d_out, int out_size, void* d_ws, size_t ws_size,
                              hipStream_t stream) {
  const float* x      = (const float*)d_in[0];
  const float* ctx    = (const float*)d_in[1];
  const float* rope_q = (const float*)d_in[2];
  const float* rope_k = (const float*)d_in[3];
  const float* Wq     = (const float*)d_in[4];
  const float* Wk     = (const float*)d_in[5];
  const float* Wv     = (const float*)d_in[6];
  const float* Wo     = (const float*)d_in[7];

  char* ws = (char*)d_ws;
  const size_t SZ_CTXB = (size_t)NB * NKV * DIMF * 2;
  const size_t SZ_XB   = (size_t)NB * NQ * DIMF * 2;
  const size_t SZ_WT   = (size_t)DIMF * DIMF * 2;
  unsigned short* ctxb = (unsigned short*)(ws);
  unsigned short* ob   = (unsigned short*)(ws);                       // alias ctxb (dead after kvgemm)
  unsigned short* xb   = (unsigned short*)(ws + SZ_CTXB);
  unsigned short* wkt  = (unsigned short*)(ws + SZ_CTXB + SZ_XB);           // wkt||wvt = wkvt[1536][768]
  unsigned short* wvt  = (unsigned short*)(ws + SZ_CTXB + SZ_XB + SZ_WT);
  unsigned short* wqt  = (unsigned short*)(ws + SZ_CTXB + SZ_XB + 2 * SZ_WT);
  unsigned short* wot  = (unsigned short*)(ws + SZ_CTXB + SZ_XB + 3 * SZ_WT);
  unsigned short* kb   = (unsigned short*)(ws + SZ_CTXB + SZ_XB + 4 * SZ_WT);
  unsigned short* vtb  = (unsigned short*)(ws + SZ_CTXB + SZ_XB + 4 * SZ_WT + SZ_CTXB);
  unsigned short* qb   = (unsigned short*)(ws + SZ_CTXB + SZ_XB + 4 * SZ_WT + 2 * SZ_CTXB);

  cvt_kernel<<<dim3(2048), dim3(256), 0, stream>>>(ctx, ctxb, NB * NKV * DIMF);
  cvt_kernel<<<dim3(1024), dim3(256), 0, stream>>>(x, xb, NB * NQ * DIMF);
  twt_kernel<<<dim3(24, 24, 4), dim3(32, 8), 0, stream>>>(Wk, Wv, Wq, Wo, wkt, wvt, wqt, wot);

  kv8_kernel<<<dim3(1536), dim3(512), 131072, stream>>>(ctxb, wkt, kb, vtb, rope_k);
  gemm_kernel<2><<<dim3(32, 6), dim3(256), 0, stream>>>(xb, wqt, qb, rope_q);

  attn_kernel<<<dim3(768), dim3(256), 0, stream>>>(qb, kb, vtb, ob);

  gemm_kernel<3><<<dim3(32, 6), dim3(256), 0, stream>>>(ob, wot, d_out, nullptr);
}

// Round 19
// 380.592 us; speedup vs baseline: 1.0605x; 1.0605x over previous
//
#include <hip/hip_runtime.h>
#include <stdint.h>

// ---------------------------------------------------------------------------
// CrossAttentionRope: x(16,256,768), ctx(16,4096,768) f32 -> out(16,256,768) f32
// R19: kv8 reverted to R17 (best, 389us: per-phase vmcnt(8), 1 barrier/phase).
//      ONE change: attn __launch_bounds__(256,3) — grid 768 = 3 blocks/CU, but
//      the old (256,2) bound capped residency at 2 blocks/CU, leaving a third
//      of the latency-bound attn grid waiting for a second scheduling round.
//      (256,3) caps VGPR at 170 (attn uses ~124 -> no spill) and makes the
//      full grid co-resident. Everything else byte-identical R17.
// ---------------------------------------------------------------------------

typedef __bf16 bf16x8 __attribute__((ext_vector_type(8)));
typedef unsigned short u16x8 __attribute__((ext_vector_type(8)));
typedef unsigned short u16x4 __attribute__((ext_vector_type(4)));
typedef uint32_t u32x4 __attribute__((ext_vector_type(4)));
typedef float f32x4 __attribute__((ext_vector_type(4)));

#define DIMF 768
#define NHEAD 12
#define NKV 4096
#define NQ 256
#define NB 16

struct alignas(8) us4 { unsigned short x, y, z, w; };

__device__ __forceinline__ unsigned short f2bf(float x) {
  uint32_t u = __float_as_uint(x);
  u += 0x7fffu + ((u >> 16) & 1u);   // round-to-nearest-even
  return (unsigned short)(u >> 16);
}

__device__ __forceinline__ uint32_t cvtpk(float a, float b) {
  uint32_t r;
  asm("v_cvt_pk_bf16_f32 %0, %1, %2" : "=v"(r) : "v"(a), "v"(b));
  return r;
}

__device__ __forceinline__ void gld_lds16(const unsigned short* g, unsigned short* l) {
  __builtin_amdgcn_global_load_lds(
      (const __attribute__((address_space(1))) uint32_t*)(uintptr_t)g,
      (__attribute__((address_space(3))) uint32_t*)(uintptr_t)l, 16, 0, 0);
}

// ---------------- convert f32 -> bf16 (vectorized, grid-stride) ------------
__global__ void cvt_kernel(const float* __restrict__ in, unsigned short* __restrict__ out, int n) {
  int stride = gridDim.x * blockDim.x * 4;
  for (int i = (blockIdx.x * blockDim.x + threadIdx.x) * 4; i < n; i += stride) {
    float4 v = *(const float4*)(in + i);
    us4 o{f2bf(v.x), f2bf(v.y), f2bf(v.z), f2bf(v.w)};
    *(us4*)(out + i) = o;
  }
}

// ---------------- weight transpose + cvt: Wt[n][k] = W[k][n] ---------------
__global__ void twt_kernel(const float* __restrict__ W0, const float* __restrict__ W1,
                           const float* __restrict__ W2, const float* __restrict__ W3,
                           unsigned short* __restrict__ O0, unsigned short* __restrict__ O1,
                           unsigned short* __restrict__ O2, unsigned short* __restrict__ O3) {
  const float* W; unsigned short* O;
  switch (blockIdx.z) {
    case 0: W = W0; O = O0; break;
    case 1: W = W1; O = O1; break;
    case 2: W = W2; O = O2; break;
    default: W = W3; O = O3; break;
  }
  __shared__ float t[32][33];
  int x0 = blockIdx.x * 32, y0 = blockIdx.y * 32;
  int tx = threadIdx.x, ty = threadIdx.y;
#pragma unroll
  for (int j = 0; j < 4; ++j)
    t[ty + 8 * j][tx] = W[(size_t)(y0 + ty + 8 * j) * DIMF + x0 + tx];
  __syncthreads();
#pragma unroll
  for (int j = 0; j < 4; ++j)
    O[(size_t)(x0 + ty + 8 * j) * DIMF + y0 + tx] = f2bf(t[tx][ty + 8 * j]);
}

// ---------------- merged KV GEMM: 256x256, 8-phase per-phase-vmcnt ----------
// (R17-proven.) Grid 1536 (256 rows x 6 cols), col-fast XCD swizzle.
// 512 thr / 8 waves; per-wave C = 128x64 interleaved.
__launch_bounds__(512, 1)
__global__ void kv8_kernel(const unsigned short* __restrict__ A,
                           const unsigned short* __restrict__ Bkv,
                           unsigned short* __restrict__ Ko,
                           unsigned short* __restrict__ Vt,
                           const float* __restrict__ rope) {
  extern __shared__ unsigned short smem[];   // 65536 shorts = 128KB
  const int t = threadIdx.x;
  const int lane = t & 63, wid = t >> 6;
  const int g = lane >> 4, lc = lane & 15;
  const int wr = wid >> 2, wc = wid & 3;

  const int swz = (blockIdx.x & 7) * 192 + (blockIdx.x >> 3);  // 1536%8==0
  const int rowBase = (swz / 6) * 256;
  const int colBase = (swz % 6) * 256;

  f32x4 acc[8][4];
#pragma unroll
  for (int m = 0; m < 8; ++m)
#pragma unroll
    for (int n = 0; n < 4; ++n)
#pragma unroll
      for (int r = 0; r < 4; ++r) acc[m][n][r] = 0.f;

  const int sr = lane >> 3;
  const int sc = (lane & 7) ^ sr;
  const unsigned short* Abase0 = A + (size_t)(rowBase + wid * 16 + sr) * DIMF + sc * 8;
  const unsigned short* Bbase0 = Bkv + (size_t)(colBase + wid * 16 + sr) * DIMF + sc * 8;

#define STAGE_A(T, h)                                                              \
  do {                                                                             \
    unsigned short* _lb = smem + (((T) & 1) * 2 + (h)) * 8192;                     \
    const unsigned short* _gb = Abase0 + (size_t)(h) * 128 * DIMF + (T) * 64;      \
    gld_lds16(_gb, _lb + (wid * 16) * 64);                                         \
    gld_lds16(_gb + (size_t)8 * DIMF, _lb + (wid * 16 + 8) * 64);                  \
  } while (0)
#define STAGE_B(T, h)                                                              \
  do {                                                                             \
    unsigned short* _lb = smem + 32768 + (((T) & 1) * 2 + (h)) * 8192;             \
    const unsigned short* _gb = Bbase0 + (size_t)(h) * 128 * DIMF + (T) * 64;      \
    gld_lds16(_gb, _lb + (wid * 16) * 64);                                         \
    gld_lds16(_gb + (size_t)8 * DIMF, _lb + (wid * 16 + 8) * 64);                  \
  } while (0)

  // prologue: T0 complete + T1's tops (order defines the FIFO wait arithmetic)
  STAGE_A(0, 0); STAGE_B(0, 0); STAGE_B(0, 1); STAGE_A(0, 1);
  STAGE_A(1, 0); STAGE_B(1, 0);

  bf16x8 af[4][2], bfr[2][2];

  for (int T = 0; T < 12; ++T) {
    const int dbuf = T & 1;
#pragma unroll
    for (int q = 0; q < 4; ++q) {
      const int ah = q >> 1, bh = q & 1;
      if (q == 0) {
        if (T < 11) asm volatile("s_waitcnt vmcnt(8)" ::: "memory");
        else        asm volatile("s_waitcnt vmcnt(4)" ::: "memory");
      } else if (q == 1) {
        if (T < 11) asm volatile("s_waitcnt vmcnt(8)" ::: "memory");
        else        asm volatile("s_waitcnt vmcnt(2)" ::: "memory");
      } else if (q == 2) {
        if (T < 11) asm volatile("s_waitcnt vmcnt(8)" ::: "memory");
        else        asm volatile("s_waitcnt vmcnt(0)" ::: "memory");
      }
      asm volatile("" ::: "memory");
      __builtin_amdgcn_s_barrier();     // all waves' needed loads visible
      asm volatile("" ::: "memory");

      const unsigned short* Ab = smem + (dbuf * 2 + ah) * 8192;
      const unsigned short* Bb = smem + 32768 + (dbuf * 2 + bh) * 8192;
      if ((q & 1) == 0) {              // A-half frags reused across 2 phases
#pragma unroll
        for (int mp = 0; mp < 4; ++mp)
#pragma unroll
          for (int kk = 0; kk < 2; ++kk) {
            int row = mp * 32 + wr * 16 + lc;
            af[mp][kk] = *(const bf16x8*)&Ab[row * 64 + (((kk * 4 + g) ^ (row & 7)) << 3)];
          }
      }
#pragma unroll
      for (int np = 0; np < 2; ++np)
#pragma unroll
        for (int kk = 0; kk < 2; ++kk) {
          int row = np * 64 + wc * 16 + lc;
          bfr[np][kk] = *(const bf16x8*)&Bb[row * 64 + (((kk * 4 + g) ^ (row & 7)) << 3)];
        }
      // stage issue (slot's readers retired before this phase's barrier):
      if (q == 0)      { if (T + 1 < 12) STAGE_B(T + 1, 1); }   // T+1:B-bot
      else if (q == 1) { if (T + 1 < 12) STAGE_A(T + 1, 1); }   // T+1:A-bot
      else if (q == 2) { if (T + 2 < 12) STAGE_A(T + 2, 0); }   // T+2:A-top
      else             { if (T + 2 < 12) STAGE_B(T + 2, 0); }   // T+2:B-top
      asm volatile("s_waitcnt lgkmcnt(0)" ::: "memory");
      __builtin_amdgcn_sched_barrier(0);   // rule #18
      __builtin_amdgcn_s_setprio(1);
#pragma unroll
      for (int mp = 0; mp < 4; ++mp)
#pragma unroll
        for (int np = 0; np < 2; ++np)
#pragma unroll
          for (int kk = 0; kk < 2; ++kk)
            acc[4 * ah + mp][2 * bh + np] = __builtin_amdgcn_mfma_f32_16x16x32_bf16(
                af[mp][kk], bfr[np][kk], acc[4 * ah + mp][2 * bh + np], 0, 0, 0);
      __builtin_amdgcn_s_setprio(0);
    }
  }
#undef STAGE_A
#undef STAGE_B

  // ---- epilogue (C/D: col=lc, row=g*4+r — proven); block-uniform branch ----
  if (colBase < 768) {   // K output + rope
#pragma unroll
    for (int m = 0; m < 8; ++m)
#pragma unroll
      for (int n = 0; n < 4; ++n)
#pragma unroll
        for (int r = 0; r < 4; ++r) {
          int p = rowBase + m * 32 + wr * 16 + g * 4 + r;
          int f = colBase + n * 64 + wc * 16 + lc;
          int d = f & 63, h = f >> 6;
          float v = acc[m][n][r];
          float vo = __shfl_xor(v, 1);
          int b = p >> 12, nkv = p & 4095;
          float sn = rope[nkv * 128 + d], cs = rope[nkv * 128 + 64 + d];
          float o = (d & 1) ? fmaf(vo, sn, v * cs) : fmaf(-vo, sn, v * cs);
          Ko[((size_t)(b * NHEAD + h) * NKV + nkv) * 64 + d] = f2bf(o);
        }
  } else {               // V output, transposed [b][h][d][nkv]
#pragma unroll
    for (int m = 0; m < 8; ++m)
#pragma unroll
      for (int n = 0; n < 4; ++n) {
        int p0 = rowBase + m * 32 + wr * 16 + g * 4;
        int b = p0 >> 12, nkv0 = p0 & 4095;
        int f = (colBase - 768) + n * 64 + wc * 16 + lc;
        int d = f & 63, h = f >> 6;
        us4 wv{f2bf(acc[m][n][0]), f2bf(acc[m][n][1]), f2bf(acc[m][n][2]), f2bf(acc[m][n][3])};
        *(us4*)&Vt[((size_t)(b * NHEAD + h) * 64 + d) * NKV + nkv0] = wv;
      }
  }
}

// ---------------- GEMM (R5/R8-proven reg-staged): Q-proj / O-proj -----------
// MODE 2: Q-proj (+rope_q, *0.125) -> Q [b][h][nq][64] bf16  [2D grid]
// MODE 3: O-proj -> out f32 [p][768]                          [2D grid]
template <int MODE>
__launch_bounds__(256, 2)
__global__ void gemm_kernel(const unsigned short* __restrict__ A,
                            const unsigned short* __restrict__ Bt,
                            void* __restrict__ outp,
                            const float* __restrict__ rope) {
  __shared__ unsigned short As[128 * 64];
  __shared__ unsigned short Bs[128 * 64];
  const int t = threadIdx.x;
  const int lane = t & 63, wid = t >> 6;
  const int g = lane >> 4, lc = lane & 15;
  const int wr = wid >> 1, wc = wid & 1;
  const int rowBase = blockIdx.x * 128, colBase = blockIdx.y * 128;

  const f32x4 z4 = {0.f, 0.f, 0.f, 0.f};
  f32x4 acc[4][4];
#pragma unroll
  for (int m = 0; m < 4; ++m)
#pragma unroll
    for (int n = 0; n < 4; ++n) acc[m][n] = z4;

  const int r0 = t >> 3;
  const int c0 = t & 7;

  bf16x8 ra[4], rbx[4];
#pragma unroll
  for (int pp = 0; pp < 4; ++pp) {
    int row = pp * 32 + r0;
    ra[pp] = *(const bf16x8*)(A + (size_t)(rowBase + row) * DIMF + c0 * 8);
    rbx[pp] = *(const bf16x8*)(Bt + (size_t)(colBase + row) * DIMF + c0 * 8);
  }

  for (int kb = 0; kb < 12; ++kb) {
    __syncthreads();
#pragma unroll
    for (int pp = 0; pp < 4; ++pp) {
      int row = pp * 32 + r0;
      int ph = ((c0 ^ (row & 7)) << 3);
      *(bf16x8*)&As[row * 64 + ph] = ra[pp];
      *(bf16x8*)&Bs[row * 64 + ph] = rbx[pp];
    }
    __syncthreads();
    if (kb + 1 < 12) {
      int kn = (kb + 1) * 64;
#pragma unroll
      for (int pp = 0; pp < 4; ++pp) {
        int row = pp * 32 + r0;
        ra[pp] = *(const bf16x8*)(A + (size_t)(rowBase + row) * DIMF + kn + c0 * 8);
        rbx[pp] = *(const bf16x8*)(Bt + (size_t)(colBase + row) * DIMF + kn + c0 * 8);
      }
    }
#pragma unroll
    for (int kk = 0; kk < 2; ++kk) {
      bf16x8 af[4], bfr[4];
#pragma unroll
      for (int m = 0; m < 4; ++m) {
        int row = wr * 64 + m * 16 + lc;
        int ch = kk * 4 + g;
        af[m] = *(const bf16x8*)&As[row * 64 + (((ch ^ (row & 7))) << 3)];
      }
#pragma unroll
      for (int n = 0; n < 4; ++n) {
        int row = wc * 64 + n * 16 + lc;
        int ch = kk * 4 + g;
        bfr[n] = *(const bf16x8*)&Bs[row * 64 + (((ch ^ (row & 7))) << 3)];
      }
#pragma unroll
      for (int m = 0; m < 4; ++m)
#pragma unroll
        for (int n = 0; n < 4; ++n)
          acc[m][n] = __builtin_amdgcn_mfma_f32_16x16x32_bf16(af[m], bfr[n], acc[m][n], 0, 0, 0);
    }
  }

  if (MODE == 2) {
    unsigned short* Ko = (unsigned short*)outp;
#pragma unroll
    for (int m = 0; m < 4; ++m)
#pragma unroll
      for (int n = 0; n < 4; ++n)
#pragma unroll
        for (int r = 0; r < 4; ++r) {
          int p = rowBase + wr * 64 + m * 16 + g * 4 + r;
          int f = colBase + wc * 64 + n * 16 + lc;
          int d = f & 63, h = f >> 6;
          float v = acc[m][n][r];
          float vo = __shfl_xor(v, 1);
          int b = p >> 8, nq = p & 255;
          float sn = rope[nq * 128 + d], cs = rope[nq * 128 + 64 + d];
          float o = (d & 1) ? fmaf(vo, sn, v * cs) : fmaf(-vo, sn, v * cs);
          Ko[((size_t)(b * NHEAD + h) * NQ + nq) * 64 + d] = f2bf(o * 0.125f);
        }
  } else {
    float* Co = (float*)outp;
#pragma unroll
    for (int m = 0; m < 4; ++m)
#pragma unroll
      for (int n = 0; n < 4; ++n)
#pragma unroll
        for (int r = 0; r < 4; ++r) {
          int p = rowBase + wr * 64 + m * 16 + g * 4 + r;
          int f = colBase + wc * 64 + n * 16 + lc;
          Co[(size_t)p * DIMF + f] = acc[m][n][r];
        }
  }
}

// ---------------- flash attention (R5-proven; bounds -> (256,3)) ------------
__launch_bounds__(256, 3)
__global__ void attn_kernel(const unsigned short* __restrict__ Qb,
                            const unsigned short* __restrict__ Kb,
                            const unsigned short* __restrict__ Vtb,
                            unsigned short* __restrict__ Ob) {
  __shared__ unsigned short Ks[128 * 64];    // [kv][d]  16KB, chunk ^= (kv&7)
  __shared__ unsigned short Vts[64 * 128];   // [d][kv'] 16KB, chunk ^= (d&15)
  const int logical = (blockIdx.x & 7) * 96 + (blockIdx.x >> 3);  // 768%8==0
  const int qt = logical & 3, bh = logical >> 2;
  const int b = bh / NHEAD, h = bh % NHEAD;
  const int t = threadIdx.x;
  const int lane = t & 63, w = t >> 6;
  const int g = lane >> 4, lc = lane & 15;
  const int qrow = qt * 64 + w * 16 + lc;

  bf16x8 qf[2];
#pragma unroll
  for (int kk = 0; kk < 2; ++kk)
    qf[kk] = *(const bf16x8*)(Qb + ((size_t)bh * NQ + qrow) * 64 + kk * 32 + g * 8);

  const f32x4 z4 = {0.f, 0.f, 0.f, 0.f};
  f32x4 oacc[4];
#pragma unroll
  for (int df = 0; df < 4; ++df) oacc[df] = z4;
  float mrun = -1e30f, lrun = 0.f;

  const int r0 = t >> 3, c0 = t & 7;
  const int d0 = t >> 4, cv = t & 15;
  const int pbase = 32 * (cv >> 2) + 16 * (cv & 1) + 4 * ((cv >> 1) & 1);
  const int ch0 = pbase >> 3, of0 = pbase & 7;
  const int ch1 = (pbase + 8) >> 3;

  u16x8 rk[4], rv[4];
#define LOAD_TILE(KT)                                                                        \
  do {                                                                                       \
    const int kvb = (KT) * 128;                                                              \
    _Pragma("unroll")                                                                        \
    for (int pp = 0; pp < 4; ++pp)                                                           \
      rk[pp] = *(const u16x8*)(Kb + ((size_t)bh * NKV + kvb + pp * 32 + r0) * 64 + c0 * 8);  \
    _Pragma("unroll")                                                                        \
    for (int pp = 0; pp < 4; ++pp)                                                           \
      rv[pp] = *(const u16x8*)(Vtb + ((size_t)bh * 64 + pp * 16 + d0) * NKV + kvb + cv * 8); \
  } while (0)

  LOAD_TILE(0);

  for (int kt = 0; kt < 32; ++kt) {
    __syncthreads();
#pragma unroll
    for (int pp = 0; pp < 4; ++pp) {
      int row = pp * 32 + r0;
      *(u16x8*)&Ks[row * 64 + ((c0 ^ (row & 7)) << 3)] = rk[pp];
    }
#pragma unroll
    for (int pp = 0; pp < 4; ++pp) {
      int d = pp * 16 + d0;
      u16x4 lo = __builtin_shufflevector(rv[pp], rv[pp], 0, 1, 2, 3);
      u16x4 hi = __builtin_shufflevector(rv[pp], rv[pp], 4, 5, 6, 7);
      *(u16x4*)&Vts[d * 128 + ((ch0 ^ (d & 15)) << 3) + of0] = lo;
      *(u16x4*)&Vts[d * 128 + ((ch1 ^ (d & 15)) << 3) + of0] = hi;
    }
    if (kt + 1 < 32) LOAD_TILE(kt + 1);
    __syncthreads();

    f32x4 s[8];
#pragma unroll
    for (int c = 0; c < 8; ++c) s[c] = z4;
#pragma unroll
    for (int kk = 0; kk < 2; ++kk)
#pragma unroll
      for (int c = 0; c < 8; ++c) {
        int row = c * 16 + lc;
        bf16x8 kf = *(const bf16x8*)&Ks[row * 64 + (((kk * 4 + g) ^ (row & 7)) << 3)];
        s[c] = __builtin_amdgcn_mfma_f32_16x16x32_bf16(kf, qf[kk], s[c], 0, 0, 0);
      }

    float mx = s[0][0];
#pragma unroll
    for (int c = 0; c < 8; ++c)
#pragma unroll
      for (int r = 0; r < 4; ++r) mx = fmaxf(mx, s[c][r]);
    mx = fmaxf(mx, __shfl_xor(mx, 16));
    mx = fmaxf(mx, __shfl_xor(mx, 32));
    float nm = fmaxf(mrun, mx);
    float al = __expf(mrun - nm);
    mrun = nm;
    float ls = 0.f;
#pragma unroll
    for (int c = 0; c < 8; ++c)
#pragma unroll
      for (int r = 0; r < 4; ++r) {
        float p = __expf(s[c][r] - nm);
        s[c][r] = p;
        ls += p;
      }
    ls += __shfl_xor(ls, 16);
    ls += __shfl_xor(ls, 32);
    lrun = lrun * al + ls;
#pragma unroll
    for (int df = 0; df < 4; ++df)
#pragma unroll
      for (int r = 0; r < 4; ++r) oacc[df][r] *= al;

    uint32_t pk[8][2];
#pragma unroll
    for (int c = 0; c < 8; ++c)
#pragma unroll
      for (int w2 = 0; w2 < 2; ++w2)
        pk[c][w2] = cvtpk(s[c][2 * w2], s[c][2 * w2 + 1]);

#pragma unroll
    for (int kb = 0; kb < 4; ++kb) {
      u32x4 pw = {pk[2 * kb][0], pk[2 * kb][1], pk[2 * kb + 1][0], pk[2 * kb + 1][1]};
      bf16x8 pa = __builtin_bit_cast(bf16x8, pw);
#pragma unroll
      for (int df = 0; df < 4; ++df) {
        int row = df * 16 + lc;
        bf16x8 vf = *(const bf16x8*)&Vts[row * 128 + (((kb * 4 + g) ^ (row & 15)) << 3)];
        oacc[df] = __builtin_amdgcn_mfma_f32_16x16x32_bf16(vf, pa, oacc[df], 0, 0, 0);
      }
    }
  }
#undef LOAD_TILE

  float inv = 1.0f / lrun;
#pragma unroll
  for (int df = 0; df < 4; ++df) {
    us4 wv{f2bf(oacc[df][0] * inv), f2bf(oacc[df][1] * inv),
           f2bf(oacc[df][2] * inv), f2bf(oacc[df][3] * inv)};
    *(us4*)&Ob[((size_t)b * NQ + qrow) * DIMF + h * 64 + df * 16 + g * 4] = wv;
  }
}

// ---------------- launch ----------------------------------------------------
extern "C" void kernel_launch(void* const* d_in, const int* in_sizes, int n_in,
                              void* d_out, int out_size, void* d_ws, size_t ws_size,
                              hipStream_t stream) {
  const float* x      = (const float*)d_in[0];
  const float* ctx    = (const float*)d_in[1];
  const float* rope_q = (const float*)d_in[2];
  const float* rope_k = (const float*)d_in[3];
  const float* Wq     = (const float*)d_in[4];
  const float* Wk     = (const float*)d_in[5];
  const float* Wv     = (const float*)d_in[6];
  const float* Wo     = (const float*)d_in[7];

  char* ws = (char*)d_ws;
  const size_t SZ_CTXB = (size_t)NB * NKV * DIMF * 2;
  const size_t SZ_XB   = (size_t)NB * NQ * DIMF * 2;
  const size_t SZ_WT   = (size_t)DIMF * DIMF * 2;
  unsigned short* ctxb = (unsigned short*)(ws);
  unsigned short* ob   = (unsigned short*)(ws);                       // alias ctxb (dead after kvgemm)
  unsigned short* xb   = (unsigned short*)(ws + SZ_CTXB);
  unsigned short* wkt  = (unsigned short*)(ws + SZ_CTXB + SZ_XB);           // wkt||wvt = wkvt[1536][768]
  unsigned short* wvt  = (unsigned short*)(ws + SZ_CTXB + SZ_XB + SZ_WT);
  unsigned short* wqt  = (unsigned short*)(ws + SZ_CTXB + SZ_XB + 2 * SZ_WT);
  unsigned short* wot  = (unsigned short*)(ws + SZ_CTXB + SZ_XB + 3 * SZ_WT);
  unsigned short* kb   = (unsigned short*)(ws + SZ_CTXB + SZ_XB + 4 * SZ_WT);
  unsigned short* vtb  = (unsigned short*)(ws + SZ_CTXB + SZ_XB + 4 * SZ_WT + SZ_CTXB);
  unsigned short* qb   = (unsigned short*)(ws + SZ_CTXB + SZ_XB + 4 * SZ_WT + 2 * SZ_CTXB);

  cvt_kernel<<<dim3(2048), dim3(256), 0, stream>>>(ctx, ctxb, NB * NKV * DIMF);
  cvt_kernel<<<dim3(1024), dim3(256), 0, stream>>>(x, xb, NB * NQ * DIMF);
  twt_kernel<<<dim3(24, 24, 4), dim3(32, 8), 0, stream>>>(Wk, Wv, Wq, Wo, wkt, wvt, wqt, wot);

  kv8_kernel<<<dim3(1536), dim3(512), 131072, stream>>>(ctxb, wkt, kb, vtb, rope_k);
  gemm_kernel<2><<<dim3(32, 6), dim3(256), 0, stream>>>(xb, wqt, qb, rope_q);

  attn_kernel<<<dim3(768), dim3(256), 0, stream>>>(qb, kb, vtb, ob);

  gemm_kernel<3><<<dim3(32, 6), dim3(256), 0, stream>>>(ob, wot, d_out, nullptr);
}

// Round 20
// 379.450 us; speedup vs baseline: 1.0637x; 1.0030x over previous
//
#include <hip/hip_runtime.h>
#include <stdint.h>

// ---------------------------------------------------------------------------
// CrossAttentionRope: x(16,256,768), ctx(16,4096,768) f32 -> out(16,256,768) f32
// R20: R19 (best, 380.6us) + T13 defer-max in attn: skip the oacc/lrun rescale
//      when __all(mx - mrun <= 8) — P bounded by e^8, f32-accum safe (m239).
//      Everything else byte-identical R19.
// ---------------------------------------------------------------------------

typedef __bf16 bf16x8 __attribute__((ext_vector_type(8)));
typedef unsigned short u16x8 __attribute__((ext_vector_type(8)));
typedef unsigned short u16x4 __attribute__((ext_vector_type(4)));
typedef uint32_t u32x4 __attribute__((ext_vector_type(4)));
typedef float f32x4 __attribute__((ext_vector_type(4)));

#define DIMF 768
#define NHEAD 12
#define NKV 4096
#define NQ 256
#define NB 16

struct alignas(8) us4 { unsigned short x, y, z, w; };

__device__ __forceinline__ unsigned short f2bf(float x) {
  uint32_t u = __float_as_uint(x);
  u += 0x7fffu + ((u >> 16) & 1u);   // round-to-nearest-even
  return (unsigned short)(u >> 16);
}

__device__ __forceinline__ uint32_t cvtpk(float a, float b) {
  uint32_t r;
  asm("v_cvt_pk_bf16_f32 %0, %1, %2" : "=v"(r) : "v"(a), "v"(b));
  return r;
}

__device__ __forceinline__ void gld_lds16(const unsigned short* g, unsigned short* l) {
  __builtin_amdgcn_global_load_lds(
      (const __attribute__((address_space(1))) uint32_t*)(uintptr_t)g,
      (__attribute__((address_space(3))) uint32_t*)(uintptr_t)l, 16, 0, 0);
}

// ---------------- convert f32 -> bf16 (vectorized, grid-stride) ------------
__global__ void cvt_kernel(const float* __restrict__ in, unsigned short* __restrict__ out, int n) {
  int stride = gridDim.x * blockDim.x * 4;
  for (int i = (blockIdx.x * blockDim.x + threadIdx.x) * 4; i < n; i += stride) {
    float4 v = *(const float4*)(in + i);
    us4 o{f2bf(v.x), f2bf(v.y), f2bf(v.z), f2bf(v.w)};
    *(us4*)(out + i) = o;
  }
}

// ---------------- weight transpose + cvt: Wt[n][k] = W[k][n] ---------------
__global__ void twt_kernel(const float* __restrict__ W0, const float* __restrict__ W1,
                           const float* __restrict__ W2, const float* __restrict__ W3,
                           unsigned short* __restrict__ O0, unsigned short* __restrict__ O1,
                           unsigned short* __restrict__ O2, unsigned short* __restrict__ O3) {
  const float* W; unsigned short* O;
  switch (blockIdx.z) {
    case 0: W = W0; O = O0; break;
    case 1: W = W1; O = O1; break;
    case 2: W = W2; O = O2; break;
    default: W = W3; O = O3; break;
  }
  __shared__ float t[32][33];
  int x0 = blockIdx.x * 32, y0 = blockIdx.y * 32;
  int tx = threadIdx.x, ty = threadIdx.y;
#pragma unroll
  for (int j = 0; j < 4; ++j)
    t[ty + 8 * j][tx] = W[(size_t)(y0 + ty + 8 * j) * DIMF + x0 + tx];
  __syncthreads();
#pragma unroll
  for (int j = 0; j < 4; ++j)
    O[(size_t)(x0 + ty + 8 * j) * DIMF + y0 + tx] = f2bf(t[tx][ty + 8 * j]);
}

// ---------------- merged KV GEMM: 256x256, 8-phase per-phase-vmcnt ----------
// (R17-proven.) Grid 1536 (256 rows x 6 cols), col-fast XCD swizzle.
// 512 thr / 8 waves; per-wave C = 128x64 interleaved.
__launch_bounds__(512, 1)
__global__ void kv8_kernel(const unsigned short* __restrict__ A,
                           const unsigned short* __restrict__ Bkv,
                           unsigned short* __restrict__ Ko,
                           unsigned short* __restrict__ Vt,
                           const float* __restrict__ rope) {
  extern __shared__ unsigned short smem[];   // 65536 shorts = 128KB
  const int t = threadIdx.x;
  const int lane = t & 63, wid = t >> 6;
  const int g = lane >> 4, lc = lane & 15;
  const int wr = wid >> 2, wc = wid & 3;

  const int swz = (blockIdx.x & 7) * 192 + (blockIdx.x >> 3);  // 1536%8==0
  const int rowBase = (swz / 6) * 256;
  const int colBase = (swz % 6) * 256;

  f32x4 acc[8][4];
#pragma unroll
  for (int m = 0; m < 8; ++m)
#pragma unroll
    for (int n = 0; n < 4; ++n)
#pragma unroll
      for (int r = 0; r < 4; ++r) acc[m][n][r] = 0.f;

  const int sr = lane >> 3;
  const int sc = (lane & 7) ^ sr;
  const unsigned short* Abase0 = A + (size_t)(rowBase + wid * 16 + sr) * DIMF + sc * 8;
  const unsigned short* Bbase0 = Bkv + (size_t)(colBase + wid * 16 + sr) * DIMF + sc * 8;

#define STAGE_A(T, h)                                                              \
  do {                                                                             \
    unsigned short* _lb = smem + (((T) & 1) * 2 + (h)) * 8192;                     \
    const unsigned short* _gb = Abase0 + (size_t)(h) * 128 * DIMF + (T) * 64;      \
    gld_lds16(_gb, _lb + (wid * 16) * 64);                                         \
    gld_lds16(_gb + (size_t)8 * DIMF, _lb + (wid * 16 + 8) * 64);                  \
  } while (0)
#define STAGE_B(T, h)                                                              \
  do {                                                                             \
    unsigned short* _lb = smem + 32768 + (((T) & 1) * 2 + (h)) * 8192;             \
    const unsigned short* _gb = Bbase0 + (size_t)(h) * 128 * DIMF + (T) * 64;      \
    gld_lds16(_gb, _lb + (wid * 16) * 64);                                         \
    gld_lds16(_gb + (size_t)8 * DIMF, _lb + (wid * 16 + 8) * 64);                  \
  } while (0)

  // prologue: T0 complete + T1's tops (order defines the FIFO wait arithmetic)
  STAGE_A(0, 0); STAGE_B(0, 0); STAGE_B(0, 1); STAGE_A(0, 1);
  STAGE_A(1, 0); STAGE_B(1, 0);

  bf16x8 af[4][2], bfr[2][2];

  for (int T = 0; T < 12; ++T) {
    const int dbuf = T & 1;
#pragma unroll
    for (int q = 0; q < 4; ++q) {
      const int ah = q >> 1, bh = q & 1;
      if (q == 0) {
        if (T < 11) asm volatile("s_waitcnt vmcnt(8)" ::: "memory");
        else        asm volatile("s_waitcnt vmcnt(4)" ::: "memory");
      } else if (q == 1) {
        if (T < 11) asm volatile("s_waitcnt vmcnt(8)" ::: "memory");
        else        asm volatile("s_waitcnt vmcnt(2)" ::: "memory");
      } else if (q == 2) {
        if (T < 11) asm volatile("s_waitcnt vmcnt(8)" ::: "memory");
        else        asm volatile("s_waitcnt vmcnt(0)" ::: "memory");
      }
      asm volatile("" ::: "memory");
      __builtin_amdgcn_s_barrier();     // all waves' needed loads visible
      asm volatile("" ::: "memory");

      const unsigned short* Ab = smem + (dbuf * 2 + ah) * 8192;
      const unsigned short* Bb = smem + 32768 + (dbuf * 2 + bh) * 8192;
      if ((q & 1) == 0) {              // A-half frags reused across 2 phases
#pragma unroll
        for (int mp = 0; mp < 4; ++mp)
#pragma unroll
          for (int kk = 0; kk < 2; ++kk) {
            int row = mp * 32 + wr * 16 + lc;
            af[mp][kk] = *(const bf16x8*)&Ab[row * 64 + (((kk * 4 + g) ^ (row & 7)) << 3)];
          }
      }
#pragma unroll
      for (int np = 0; np < 2; ++np)
#pragma unroll
        for (int kk = 0; kk < 2; ++kk) {
          int row = np * 64 + wc * 16 + lc;
          bfr[np][kk] = *(const bf16x8*)&Bb[row * 64 + (((kk * 4 + g) ^ (row & 7)) << 3)];
        }
      // stage issue (slot's readers retired before this phase's barrier):
      if (q == 0)      { if (T + 1 < 12) STAGE_B(T + 1, 1); }   // T+1:B-bot
      else if (q == 1) { if (T + 1 < 12) STAGE_A(T + 1, 1); }   // T+1:A-bot
      else if (q == 2) { if (T + 2 < 12) STAGE_A(T + 2, 0); }   // T+2:A-top
      else             { if (T + 2 < 12) STAGE_B(T + 2, 0); }   // T+2:B-top
      asm volatile("s_waitcnt lgkmcnt(0)" ::: "memory");
      __builtin_amdgcn_sched_barrier(0);   // rule #18
      __builtin_amdgcn_s_setprio(1);
#pragma unroll
      for (int mp = 0; mp < 4; ++mp)
#pragma unroll
        for (int np = 0; np < 2; ++np)
#pragma unroll
          for (int kk = 0; kk < 2; ++kk)
            acc[4 * ah + mp][2 * bh + np] = __builtin_amdgcn_mfma_f32_16x16x32_bf16(
                af[mp][kk], bfr[np][kk], acc[4 * ah + mp][2 * bh + np], 0, 0, 0);
      __builtin_amdgcn_s_setprio(0);
    }
  }
#undef STAGE_A
#undef STAGE_B

  // ---- epilogue (C/D: col=lc, row=g*4+r — proven); block-uniform branch ----
  if (colBase < 768) {   // K output + rope
#pragma unroll
    for (int m = 0; m < 8; ++m)
#pragma unroll
      for (int n = 0; n < 4; ++n)
#pragma unroll
        for (int r = 0; r < 4; ++r) {
          int p = rowBase + m * 32 + wr * 16 + g * 4 + r;
          int f = colBase + n * 64 + wc * 16 + lc;
          int d = f & 63, h = f >> 6;
          float v = acc[m][n][r];
          float vo = __shfl_xor(v, 1);
          int b = p >> 12, nkv = p & 4095;
          float sn = rope[nkv * 128 + d], cs = rope[nkv * 128 + 64 + d];
          float o = (d & 1) ? fmaf(vo, sn, v * cs) : fmaf(-vo, sn, v * cs);
          Ko[((size_t)(b * NHEAD + h) * NKV + nkv) * 64 + d] = f2bf(o);
        }
  } else {               // V output, transposed [b][h][d][nkv]
#pragma unroll
    for (int m = 0; m < 8; ++m)
#pragma unroll
      for (int n = 0; n < 4; ++n) {
        int p0 = rowBase + m * 32 + wr * 16 + g * 4;
        int b = p0 >> 12, nkv0 = p0 & 4095;
        int f = (colBase - 768) + n * 64 + wc * 16 + lc;
        int d = f & 63, h = f >> 6;
        us4 wv{f2bf(acc[m][n][0]), f2bf(acc[m][n][1]), f2bf(acc[m][n][2]), f2bf(acc[m][n][3])};
        *(us4*)&Vt[((size_t)(b * NHEAD + h) * 64 + d) * NKV + nkv0] = wv;
      }
  }
}

// ---------------- GEMM (R5/R8-proven reg-staged): Q-proj / O-proj -----------
// MODE 2: Q-proj (+rope_q, *0.125) -> Q [b][h][nq][64] bf16  [2D grid]
// MODE 3: O-proj -> out f32 [p][768]                          [2D grid]
template <int MODE>
__launch_bounds__(256, 2)
__global__ void gemm_kernel(const unsigned short* __restrict__ A,
                            const unsigned short* __restrict__ Bt,
                            void* __restrict__ outp,
                            const float* __restrict__ rope) {
  __shared__ unsigned short As[128 * 64];
  __shared__ unsigned short Bs[128 * 64];
  const int t = threadIdx.x;
  const int lane = t & 63, wid = t >> 6;
  const int g = lane >> 4, lc = lane & 15;
  const int wr = wid >> 1, wc = wid & 1;
  const int rowBase = blockIdx.x * 128, colBase = blockIdx.y * 128;

  const f32x4 z4 = {0.f, 0.f, 0.f, 0.f};
  f32x4 acc[4][4];
#pragma unroll
  for (int m = 0; m < 4; ++m)
#pragma unroll
    for (int n = 0; n < 4; ++n) acc[m][n] = z4;

  const int r0 = t >> 3;
  const int c0 = t & 7;

  bf16x8 ra[4], rbx[4];
#pragma unroll
  for (int pp = 0; pp < 4; ++pp) {
    int row = pp * 32 + r0;
    ra[pp] = *(const bf16x8*)(A + (size_t)(rowBase + row) * DIMF + c0 * 8);
    rbx[pp] = *(const bf16x8*)(Bt + (size_t)(colBase + row) * DIMF + c0 * 8);
  }

  for (int kb = 0; kb < 12; ++kb) {
    __syncthreads();
#pragma unroll
    for (int pp = 0; pp < 4; ++pp) {
      int row = pp * 32 + r0;
      int ph = ((c0 ^ (row & 7)) << 3);
      *(bf16x8*)&As[row * 64 + ph] = ra[pp];
      *(bf16x8*)&Bs[row * 64 + ph] = rbx[pp];
    }
    __syncthreads();
    if (kb + 1 < 12) {
      int kn = (kb + 1) * 64;
#pragma unroll
      for (int pp = 0; pp < 4; ++pp) {
        int row = pp * 32 + r0;
        ra[pp] = *(const bf16x8*)(A + (size_t)(rowBase + row) * DIMF + kn + c0 * 8);
        rbx[pp] = *(const bf16x8*)(Bt + (size_t)(colBase + row) * DIMF + kn + c0 * 8);
      }
    }
#pragma unroll
    for (int kk = 0; kk < 2; ++kk) {
      bf16x8 af[4], bfr[4];
#pragma unroll
      for (int m = 0; m < 4; ++m) {
        int row = wr * 64 + m * 16 + lc;
        int ch = kk * 4 + g;
        af[m] = *(const bf16x8*)&As[row * 64 + (((ch ^ (row & 7))) << 3)];
      }
#pragma unroll
      for (int n = 0; n < 4; ++n) {
        int row = wc * 64 + n * 16 + lc;
        int ch = kk * 4 + g;
        bfr[n] = *(const bf16x8*)&Bs[row * 64 + (((ch ^ (row & 7))) << 3)];
      }
#pragma unroll
      for (int m = 0; m < 4; ++m)
#pragma unroll
        for (int n = 0; n < 4; ++n)
          acc[m][n] = __builtin_amdgcn_mfma_f32_16x16x32_bf16(af[m], bfr[n], acc[m][n], 0, 0, 0);
    }
  }

  if (MODE == 2) {
    unsigned short* Ko = (unsigned short*)outp;
#pragma unroll
    for (int m = 0; m < 4; ++m)
#pragma unroll
      for (int n = 0; n < 4; ++n)
#pragma unroll
        for (int r = 0; r < 4; ++r) {
          int p = rowBase + wr * 64 + m * 16 + g * 4 + r;
          int f = colBase + wc * 64 + n * 16 + lc;
          int d = f & 63, h = f >> 6;
          float v = acc[m][n][r];
          float vo = __shfl_xor(v, 1);
          int b = p >> 8, nq = p & 255;
          float sn = rope[nq * 128 + d], cs = rope[nq * 128 + 64 + d];
          float o = (d & 1) ? fmaf(vo, sn, v * cs) : fmaf(-vo, sn, v * cs);
          Ko[((size_t)(b * NHEAD + h) * NQ + nq) * 64 + d] = f2bf(o * 0.125f);
        }
  } else {
    float* Co = (float*)outp;
#pragma unroll
    for (int m = 0; m < 4; ++m)
#pragma unroll
      for (int n = 0; n < 4; ++n)
#pragma unroll
        for (int r = 0; r < 4; ++r) {
          int p = rowBase + wr * 64 + m * 16 + g * 4 + r;
          int f = colBase + wc * 64 + n * 16 + lc;
          Co[(size_t)p * DIMF + f] = acc[m][n][r];
        }
  }
}

// ---------------- flash attention (R19 + T13 defer-max) ---------------------
__launch_bounds__(256, 3)
__global__ void attn_kernel(const unsigned short* __restrict__ Qb,
                            const unsigned short* __restrict__ Kb,
                            const unsigned short* __restrict__ Vtb,
                            unsigned short* __restrict__ Ob) {
  __shared__ unsigned short Ks[128 * 64];    // [kv][d]  16KB, chunk ^= (kv&7)
  __shared__ unsigned short Vts[64 * 128];   // [d][kv'] 16KB, chunk ^= (d&15)
  const int logical = (blockIdx.x & 7) * 96 + (blockIdx.x >> 3);  // 768%8==0
  const int qt = logical & 3, bh = logical >> 2;
  const int b = bh / NHEAD, h = bh % NHEAD;
  const int t = threadIdx.x;
  const int lane = t & 63, w = t >> 6;
  const int g = lane >> 4, lc = lane & 15;
  const int qrow = qt * 64 + w * 16 + lc;

  bf16x8 qf[2];
#pragma unroll
  for (int kk = 0; kk < 2; ++kk)
    qf[kk] = *(const bf16x8*)(Qb + ((size_t)bh * NQ + qrow) * 64 + kk * 32 + g * 8);

  const f32x4 z4 = {0.f, 0.f, 0.f, 0.f};
  f32x4 oacc[4];
#pragma unroll
  for (int df = 0; df < 4; ++df) oacc[df] = z4;
  float mrun = -1e30f, lrun = 0.f;

  const int r0 = t >> 3, c0 = t & 7;
  const int d0 = t >> 4, cv = t & 15;
  const int pbase = 32 * (cv >> 2) + 16 * (cv & 1) + 4 * ((cv >> 1) & 1);
  const int ch0 = pbase >> 3, of0 = pbase & 7;
  const int ch1 = (pbase + 8) >> 3;

  u16x8 rk[4], rv[4];
#define LOAD_TILE(KT)                                                                        \
  do {                                                                                       \
    const int kvb = (KT) * 128;                                                              \
    _Pragma("unroll")                                                                        \
    for (int pp = 0; pp < 4; ++pp)                                                           \
      rk[pp] = *(const u16x8*)(Kb + ((size_t)bh * NKV + kvb + pp * 32 + r0) * 64 + c0 * 8);  \
    _Pragma("unroll")                                                                        \
    for (int pp = 0; pp < 4; ++pp)                                                           \
      rv[pp] = *(const u16x8*)(Vtb + ((size_t)bh * 64 + pp * 16 + d0) * NKV + kvb + cv * 8); \
  } while (0)

  LOAD_TILE(0);

  for (int kt = 0; kt < 32; ++kt) {
    __syncthreads();
#pragma unroll
    for (int pp = 0; pp < 4; ++pp) {
      int row = pp * 32 + r0;
      *(u16x8*)&Ks[row * 64 + ((c0 ^ (row & 7)) << 3)] = rk[pp];
    }
#pragma unroll
    for (int pp = 0; pp < 4; ++pp) {
      int d = pp * 16 + d0;
      u16x4 lo = __builtin_shufflevector(rv[pp], rv[pp], 0, 1, 2, 3);
      u16x4 hi = __builtin_shufflevector(rv[pp], rv[pp], 4, 5, 6, 7);
      *(u16x4*)&Vts[d * 128 + ((ch0 ^ (d & 15)) << 3) + of0] = lo;
      *(u16x4*)&Vts[d * 128 + ((ch1 ^ (d & 15)) << 3) + of0] = hi;
    }
    if (kt + 1 < 32) LOAD_TILE(kt + 1);
    __syncthreads();

    f32x4 s[8];
#pragma unroll
    for (int c = 0; c < 8; ++c) s[c] = z4;
#pragma unroll
    for (int kk = 0; kk < 2; ++kk)
#pragma unroll
      for (int c = 0; c < 8; ++c) {
        int row = c * 16 + lc;
        bf16x8 kf = *(const bf16x8*)&Ks[row * 64 + (((kk * 4 + g) ^ (row & 7)) << 3)];
        s[c] = __builtin_amdgcn_mfma_f32_16x16x32_bf16(kf, qf[kk], s[c], 0, 0, 0);
      }

    float mx = s[0][0];
#pragma unroll
    for (int c = 0; c < 8; ++c)
#pragma unroll
      for (int r = 0; r < 4; ++r) mx = fmaxf(mx, s[c][r]);
    mx = fmaxf(mx, __shfl_xor(mx, 16));
    mx = fmaxf(mx, __shfl_xor(mx, 32));
    // T13 defer-max: skip rescale when max growth <= 8 (P bounded by e^8)
    if (!__all(mx - mrun <= 8.f)) {
      float nm = fmaxf(mrun, mx);
      float al = __expf(mrun - nm);
      mrun = nm;
      lrun *= al;
#pragma unroll
      for (int df = 0; df < 4; ++df)
#pragma unroll
        for (int r = 0; r < 4; ++r) oacc[df][r] *= al;
    }
    float ls = 0.f;
#pragma unroll
    for (int c = 0; c < 8; ++c)
#pragma unroll
      for (int r = 0; r < 4; ++r) {
        float p = __expf(s[c][r] - mrun);
        s[c][r] = p;
        ls += p;
      }
    ls += __shfl_xor(ls, 16);
    ls += __shfl_xor(ls, 32);
    lrun += ls;

    uint32_t pk[8][2];
#pragma unroll
    for (int c = 0; c < 8; ++c)
#pragma unroll
      for (int w2 = 0; w2 < 2; ++w2)
        pk[c][w2] = cvtpk(s[c][2 * w2], s[c][2 * w2 + 1]);

#pragma unroll
    for (int kb = 0; kb < 4; ++kb) {
      u32x4 pw = {pk[2 * kb][0], pk[2 * kb][1], pk[2 * kb + 1][0], pk[2 * kb + 1][1]};
      bf16x8 pa = __builtin_bit_cast(bf16x8, pw);
#pragma unroll
      for (int df = 0; df < 4; ++df) {
        int row = df * 16 + lc;
        bf16x8 vf = *(const bf16x8*)&Vts[row * 128 + (((kb * 4 + g) ^ (row & 15)) << 3)];
        oacc[df] = __builtin_amdgcn_mfma_f32_16x16x32_bf16(vf, pa, oacc[df], 0, 0, 0);
      }
    }
  }
#undef LOAD_TILE

  float inv = 1.0f / lrun;
#pragma unroll
  for (int df = 0; df < 4; ++df) {
    us4 wv{f2bf(oacc[df][0] * inv), f2bf(oacc[df][1] * inv),
           f2bf(oacc[df][2] * inv), f2bf(oacc[df][3] * inv)};
    *(us4*)&Ob[((size_t)b * NQ + qrow) * DIMF + h * 64 + df * 16 + g * 4] = wv;
  }
}

// ---------------- launch ----------------------------------------------------
extern "C" void kernel_launch(void* const* d_in, const int* in_sizes, int n_in,
                              void* d_out, int out_size, void* d_ws, size_t ws_size,
                              hipStream_t stream) {
  const float* x      = (const float*)d_in[0];
  const float* ctx    = (const float*)d_in[1];
  const float* rope_q = (const float*)d_in[2];
  const float* rope_k = (const float*)d_in[3];
  const float* Wq     = (const float*)d_in[4];
  const float* Wk     = (const float*)d_in[5];
  const float* Wv     = (const float*)d_in[6];
  const float* Wo     = (const float*)d_in[7];

  char* ws = (char*)d_ws;
  const size_t SZ_CTXB = (size_t)NB * NKV * DIMF * 2;
  const size_t SZ_XB   = (size_t)NB * NQ * DIMF * 2;
  const size_t SZ_WT   = (size_t)DIMF * DIMF * 2;
  unsigned short* ctxb = (unsigned short*)(ws);
  unsigned short* ob   = (unsigned short*)(ws);                       // alias ctxb (dead after kvgemm)
  unsigned short* xb   = (unsigned short*)(ws + SZ_CTXB);
  unsigned short* wkt  = (unsigned short*)(ws + SZ_CTXB + SZ_XB);           // wkt||wvt = wkvt[1536][768]
  unsigned short* wvt  = (unsigned short*)(ws + SZ_CTXB + SZ_XB + SZ_WT);
  unsigned short* wqt  = (unsigned short*)(ws + SZ_CTXB + SZ_XB + 2 * SZ_WT);
  unsigned short* wot  = (unsigned short*)(ws + SZ_CTXB + SZ_XB + 3 * SZ_WT);
  unsigned short* kb   = (unsigned short*)(ws + SZ_CTXB + SZ_XB + 4 * SZ_WT);
  unsigned short* vtb  = (unsigned short*)(ws + SZ_CTXB + SZ_XB + 4 * SZ_WT + SZ_CTXB);
  unsigned short* qb   = (unsigned short*)(ws + SZ_CTXB + SZ_XB + 4 * SZ_WT + 2 * SZ_CTXB);

  cvt_kernel<<<dim3(2048), dim3(256), 0, stream>>>(ctx, ctxb, NB * NKV * DIMF);
  cvt_kernel<<<dim3(1024), dim3(256), 0, stream>>>(x, xb, NB * NQ * DIMF);
  twt_kernel<<<dim3(24, 24, 4), dim3(32, 8), 0, stream>>>(Wk, Wv, Wq, Wo, wkt, wvt, wqt, wot);

  kv8_kernel<<<dim3(1536), dim3(512), 131072, stream>>>(ctxb, wkt, kb, vtb, rope_k);
  gemm_kernel<2><<<dim3(32, 6), dim3(256), 0, stream>>>(xb, wqt, qb, rope_q);

  attn_kernel<<<dim3(768), dim3(256), 0, stream>>>(qb, kb, vtb, ob);

  gemm_kernel<3><<<dim3(32, 6), dim3(256), 0, stream>>>(ob, wot, d_out, nullptr);
}

// Round 21
// 377.354 us; speedup vs baseline: 1.0696x; 1.0056x over previous
//
#include <hip/hip_runtime.h>
#include <stdint.h>

// ---------------------------------------------------------------------------
// CrossAttentionRope: x(16,256,768), ctx(16,4096,768) f32 -> out(16,256,768) f32
// R21: R20 (best, 379.4us) + T5 s_setprio around attn's QK^T and PV MFMA
//      clusters (attn = 3 independent blocks/CU -> cross-block phase
//      diversity = m191's positive regime). Everything else byte-identical.
// ---------------------------------------------------------------------------

typedef __bf16 bf16x8 __attribute__((ext_vector_type(8)));
typedef unsigned short u16x8 __attribute__((ext_vector_type(8)));
typedef unsigned short u16x4 __attribute__((ext_vector_type(4)));
typedef uint32_t u32x4 __attribute__((ext_vector_type(4)));
typedef float f32x4 __attribute__((ext_vector_type(4)));

#define DIMF 768
#define NHEAD 12
#define NKV 4096
#define NQ 256
#define NB 16

struct alignas(8) us4 { unsigned short x, y, z, w; };

__device__ __forceinline__ unsigned short f2bf(float x) {
  uint32_t u = __float_as_uint(x);
  u += 0x7fffu + ((u >> 16) & 1u);   // round-to-nearest-even
  return (unsigned short)(u >> 16);
}

__device__ __forceinline__ uint32_t cvtpk(float a, float b) {
  uint32_t r;
  asm("v_cvt_pk_bf16_f32 %0, %1, %2" : "=v"(r) : "v"(a), "v"(b));
  return r;
}

__device__ __forceinline__ void gld_lds16(const unsigned short* g, unsigned short* l) {
  __builtin_amdgcn_global_load_lds(
      (const __attribute__((address_space(1))) uint32_t*)(uintptr_t)g,
      (__attribute__((address_space(3))) uint32_t*)(uintptr_t)l, 16, 0, 0);
}

// ---------------- convert f32 -> bf16 (vectorized, grid-stride) ------------
__global__ void cvt_kernel(const float* __restrict__ in, unsigned short* __restrict__ out, int n) {
  int stride = gridDim.x * blockDim.x * 4;
  for (int i = (blockIdx.x * blockDim.x + threadIdx.x) * 4; i < n; i += stride) {
    float4 v = *(const float4*)(in + i);
    us4 o{f2bf(v.x), f2bf(v.y), f2bf(v.z), f2bf(v.w)};
    *(us4*)(out + i) = o;
  }
}

// ---------------- weight transpose + cvt: Wt[n][k] = W[k][n] ---------------
__global__ void twt_kernel(const float* __restrict__ W0, const float* __restrict__ W1,
                           const float* __restrict__ W2, const float* __restrict__ W3,
                           unsigned short* __restrict__ O0, unsigned short* __restrict__ O1,
                           unsigned short* __restrict__ O2, unsigned short* __restrict__ O3) {
  const float* W; unsigned short* O;
  switch (blockIdx.z) {
    case 0: W = W0; O = O0; break;
    case 1: W = W1; O = O1; break;
    case 2: W = W2; O = O2; break;
    default: W = W3; O = O3; break;
  }
  __shared__ float t[32][33];
  int x0 = blockIdx.x * 32, y0 = blockIdx.y * 32;
  int tx = threadIdx.x, ty = threadIdx.y;
#pragma unroll
  for (int j = 0; j < 4; ++j)
    t[ty + 8 * j][tx] = W[(size_t)(y0 + ty + 8 * j) * DIMF + x0 + tx];
  __syncthreads();
#pragma unroll
  for (int j = 0; j < 4; ++j)
    O[(size_t)(x0 + ty + 8 * j) * DIMF + y0 + tx] = f2bf(t[tx][ty + 8 * j]);
}

// ---------------- merged KV GEMM: 256x256, 8-phase per-phase-vmcnt ----------
// (R17-proven.) Grid 1536 (256 rows x 6 cols), col-fast XCD swizzle.
// 512 thr / 8 waves; per-wave C = 128x64 interleaved.
__launch_bounds__(512, 1)
__global__ void kv8_kernel(const unsigned short* __restrict__ A,
                           const unsigned short* __restrict__ Bkv,
                           unsigned short* __restrict__ Ko,
                           unsigned short* __restrict__ Vt,
                           const float* __restrict__ rope) {
  extern __shared__ unsigned short smem[];   // 65536 shorts = 128KB
  const int t = threadIdx.x;
  const int lane = t & 63, wid = t >> 6;
  const int g = lane >> 4, lc = lane & 15;
  const int wr = wid >> 2, wc = wid & 3;

  const int swz = (blockIdx.x & 7) * 192 + (blockIdx.x >> 3);  // 1536%8==0
  const int rowBase = (swz / 6) * 256;
  const int colBase = (swz % 6) * 256;

  f32x4 acc[8][4];
#pragma unroll
  for (int m = 0; m < 8; ++m)
#pragma unroll
    for (int n = 0; n < 4; ++n)
#pragma unroll
      for (int r = 0; r < 4; ++r) acc[m][n][r] = 0.f;

  const int sr = lane >> 3;
  const int sc = (lane & 7) ^ sr;
  const unsigned short* Abase0 = A + (size_t)(rowBase + wid * 16 + sr) * DIMF + sc * 8;
  const unsigned short* Bbase0 = Bkv + (size_t)(colBase + wid * 16 + sr) * DIMF + sc * 8;

#define STAGE_A(T, h)                                                              \
  do {                                                                             \
    unsigned short* _lb = smem + (((T) & 1) * 2 + (h)) * 8192;                     \
    const unsigned short* _gb = Abase0 + (size_t)(h) * 128 * DIMF + (T) * 64;      \
    gld_lds16(_gb, _lb + (wid * 16) * 64);                                         \
    gld_lds16(_gb + (size_t)8 * DIMF, _lb + (wid * 16 + 8) * 64);                  \
  } while (0)
#define STAGE_B(T, h)                                                              \
  do {                                                                             \
    unsigned short* _lb = smem + 32768 + (((T) & 1) * 2 + (h)) * 8192;             \
    const unsigned short* _gb = Bbase0 + (size_t)(h) * 128 * DIMF + (T) * 64;      \
    gld_lds16(_gb, _lb + (wid * 16) * 64);                                         \
    gld_lds16(_gb + (size_t)8 * DIMF, _lb + (wid * 16 + 8) * 64);                  \
  } while (0)

  // prologue: T0 complete + T1's tops (order defines the FIFO wait arithmetic)
  STAGE_A(0, 0); STAGE_B(0, 0); STAGE_B(0, 1); STAGE_A(0, 1);
  STAGE_A(1, 0); STAGE_B(1, 0);

  bf16x8 af[4][2], bfr[2][2];

  for (int T = 0; T < 12; ++T) {
    const int dbuf = T & 1;
#pragma unroll
    for (int q = 0; q < 4; ++q) {
      const int ah = q >> 1, bh = q & 1;
      if (q == 0) {
        if (T < 11) asm volatile("s_waitcnt vmcnt(8)" ::: "memory");
        else        asm volatile("s_waitcnt vmcnt(4)" ::: "memory");
      } else if (q == 1) {
        if (T < 11) asm volatile("s_waitcnt vmcnt(8)" ::: "memory");
        else        asm volatile("s_waitcnt vmcnt(2)" ::: "memory");
      } else if (q == 2) {
        if (T < 11) asm volatile("s_waitcnt vmcnt(8)" ::: "memory");
        else        asm volatile("s_waitcnt vmcnt(0)" ::: "memory");
      }
      asm volatile("" ::: "memory");
      __builtin_amdgcn_s_barrier();     // all waves' needed loads visible
      asm volatile("" ::: "memory");

      const unsigned short* Ab = smem + (dbuf * 2 + ah) * 8192;
      const unsigned short* Bb = smem + 32768 + (dbuf * 2 + bh) * 8192;
      if ((q & 1) == 0) {              // A-half frags reused across 2 phases
#pragma unroll
        for (int mp = 0; mp < 4; ++mp)
#pragma unroll
          for (int kk = 0; kk < 2; ++kk) {
            int row = mp * 32 + wr * 16 + lc;
            af[mp][kk] = *(const bf16x8*)&Ab[row * 64 + (((kk * 4 + g) ^ (row & 7)) << 3)];
          }
      }
#pragma unroll
      for (int np = 0; np < 2; ++np)
#pragma unroll
        for (int kk = 0; kk < 2; ++kk) {
          int row = np * 64 + wc * 16 + lc;
          bfr[np][kk] = *(const bf16x8*)&Bb[row * 64 + (((kk * 4 + g) ^ (row & 7)) << 3)];
        }
      // stage issue (slot's readers retired before this phase's barrier):
      if (q == 0)      { if (T + 1 < 12) STAGE_B(T + 1, 1); }   // T+1:B-bot
      else if (q == 1) { if (T + 1 < 12) STAGE_A(T + 1, 1); }   // T+1:A-bot
      else if (q == 2) { if (T + 2 < 12) STAGE_A(T + 2, 0); }   // T+2:A-top
      else             { if (T + 2 < 12) STAGE_B(T + 2, 0); }   // T+2:B-top
      asm volatile("s_waitcnt lgkmcnt(0)" ::: "memory");
      __builtin_amdgcn_sched_barrier(0);   // rule #18
      __builtin_amdgcn_s_setprio(1);
#pragma unroll
      for (int mp = 0; mp < 4; ++mp)
#pragma unroll
        for (int np = 0; np < 2; ++np)
#pragma unroll
          for (int kk = 0; kk < 2; ++kk)
            acc[4 * ah + mp][2 * bh + np] = __builtin_amdgcn_mfma_f32_16x16x32_bf16(
                af[mp][kk], bfr[np][kk], acc[4 * ah + mp][2 * bh + np], 0, 0, 0);
      __builtin_amdgcn_s_setprio(0);
    }
  }
#undef STAGE_A
#undef STAGE_B

  // ---- epilogue (C/D: col=lc, row=g*4+r — proven); block-uniform branch ----
  if (colBase < 768) {   // K output + rope
#pragma unroll
    for (int m = 0; m < 8; ++m)
#pragma unroll
      for (int n = 0; n < 4; ++n)
#pragma unroll
        for (int r = 0; r < 4; ++r) {
          int p = rowBase + m * 32 + wr * 16 + g * 4 + r;
          int f = colBase + n * 64 + wc * 16 + lc;
          int d = f & 63, h = f >> 6;
          float v = acc[m][n][r];
          float vo = __shfl_xor(v, 1);
          int b = p >> 12, nkv = p & 4095;
          float sn = rope[nkv * 128 + d], cs = rope[nkv * 128 + 64 + d];
          float o = (d & 1) ? fmaf(vo, sn, v * cs) : fmaf(-vo, sn, v * cs);
          Ko[((size_t)(b * NHEAD + h) * NKV + nkv) * 64 + d] = f2bf(o);
        }
  } else {               // V output, transposed [b][h][d][nkv]
#pragma unroll
    for (int m = 0; m < 8; ++m)
#pragma unroll
      for (int n = 0; n < 4; ++n) {
        int p0 = rowBase + m * 32 + wr * 16 + g * 4;
        int b = p0 >> 12, nkv0 = p0 & 4095;
        int f = (colBase - 768) + n * 64 + wc * 16 + lc;
        int d = f & 63, h = f >> 6;
        us4 wv{f2bf(acc[m][n][0]), f2bf(acc[m][n][1]), f2bf(acc[m][n][2]), f2bf(acc[m][n][3])};
        *(us4*)&Vt[((size_t)(b * NHEAD + h) * 64 + d) * NKV + nkv0] = wv;
      }
  }
}

// ---------------- GEMM (R5/R8-proven reg-staged): Q-proj / O-proj -----------
// MODE 2: Q-proj (+rope_q, *0.125) -> Q [b][h][nq][64] bf16  [2D grid]
// MODE 3: O-proj -> out f32 [p][768]                          [2D grid]
template <int MODE>
__launch_bounds__(256, 2)
__global__ void gemm_kernel(const unsigned short* __restrict__ A,
                            const unsigned short* __restrict__ Bt,
                            void* __restrict__ outp,
                            const float* __restrict__ rope) {
  __shared__ unsigned short As[128 * 64];
  __shared__ unsigned short Bs[128 * 64];
  const int t = threadIdx.x;
  const int lane = t & 63, wid = t >> 6;
  const int g = lane >> 4, lc = lane & 15;
  const int wr = wid >> 1, wc = wid & 1;
  const int rowBase = blockIdx.x * 128, colBase = blockIdx.y * 128;

  const f32x4 z4 = {0.f, 0.f, 0.f, 0.f};
  f32x4 acc[4][4];
#pragma unroll
  for (int m = 0; m < 4; ++m)
#pragma unroll
    for (int n = 0; n < 4; ++n) acc[m][n] = z4;

  const int r0 = t >> 3;
  const int c0 = t & 7;

  bf16x8 ra[4], rbx[4];
#pragma unroll
  for (int pp = 0; pp < 4; ++pp) {
    int row = pp * 32 + r0;
    ra[pp] = *(const bf16x8*)(A + (size_t)(rowBase + row) * DIMF + c0 * 8);
    rbx[pp] = *(const bf16x8*)(Bt + (size_t)(colBase + row) * DIMF + c0 * 8);
  }

  for (int kb = 0; kb < 12; ++kb) {
    __syncthreads();
#pragma unroll
    for (int pp = 0; pp < 4; ++pp) {
      int row = pp * 32 + r0;
      int ph = ((c0 ^ (row & 7)) << 3);
      *(bf16x8*)&As[row * 64 + ph] = ra[pp];
      *(bf16x8*)&Bs[row * 64 + ph] = rbx[pp];
    }
    __syncthreads();
    if (kb + 1 < 12) {
      int kn = (kb + 1) * 64;
#pragma unroll
      for (int pp = 0; pp < 4; ++pp) {
        int row = pp * 32 + r0;
        ra[pp] = *(const bf16x8*)(A + (size_t)(rowBase + row) * DIMF + kn + c0 * 8);
        rbx[pp] = *(const bf16x8*)(Bt + (size_t)(colBase + row) * DIMF + kn + c0 * 8);
      }
    }
#pragma unroll
    for (int kk = 0; kk < 2; ++kk) {
      bf16x8 af[4], bfr[4];
#pragma unroll
      for (int m = 0; m < 4; ++m) {
        int row = wr * 64 + m * 16 + lc;
        int ch = kk * 4 + g;
        af[m] = *(const bf16x8*)&As[row * 64 + (((ch ^ (row & 7))) << 3)];
      }
#pragma unroll
      for (int n = 0; n < 4; ++n) {
        int row = wc * 64 + n * 16 + lc;
        int ch = kk * 4 + g;
        bfr[n] = *(const bf16x8*)&Bs[row * 64 + (((ch ^ (row & 7))) << 3)];
      }
#pragma unroll
      for (int m = 0; m < 4; ++m)
#pragma unroll
        for (int n = 0; n < 4; ++n)
          acc[m][n] = __builtin_amdgcn_mfma_f32_16x16x32_bf16(af[m], bfr[n], acc[m][n], 0, 0, 0);
    }
  }

  if (MODE == 2) {
    unsigned short* Ko = (unsigned short*)outp;
#pragma unroll
    for (int m = 0; m < 4; ++m)
#pragma unroll
      for (int n = 0; n < 4; ++n)
#pragma unroll
        for (int r = 0; r < 4; ++r) {
          int p = rowBase + wr * 64 + m * 16 + g * 4 + r;
          int f = colBase + wc * 64 + n * 16 + lc;
          int d = f & 63, h = f >> 6;
          float v = acc[m][n][r];
          float vo = __shfl_xor(v, 1);
          int b = p >> 8, nq = p & 255;
          float sn = rope[nq * 128 + d], cs = rope[nq * 128 + 64 + d];
          float o = (d & 1) ? fmaf(vo, sn, v * cs) : fmaf(-vo, sn, v * cs);
          Ko[((size_t)(b * NHEAD + h) * NQ + nq) * 64 + d] = f2bf(o * 0.125f);
        }
  } else {
    float* Co = (float*)outp;
#pragma unroll
    for (int m = 0; m < 4; ++m)
#pragma unroll
      for (int n = 0; n < 4; ++n)
#pragma unroll
        for (int r = 0; r < 4; ++r) {
          int p = rowBase + wr * 64 + m * 16 + g * 4 + r;
          int f = colBase + wc * 64 + n * 16 + lc;
          Co[(size_t)p * DIMF + f] = acc[m][n][r];
        }
  }
}

// ---------------- flash attention (R20 + T5 setprio on MFMA clusters) -------
__launch_bounds__(256, 3)
__global__ void attn_kernel(const unsigned short* __restrict__ Qb,
                            const unsigned short* __restrict__ Kb,
                            const unsigned short* __restrict__ Vtb,
                            unsigned short* __restrict__ Ob) {
  __shared__ unsigned short Ks[128 * 64];    // [kv][d]  16KB, chunk ^= (kv&7)
  __shared__ unsigned short Vts[64 * 128];   // [d][kv'] 16KB, chunk ^= (d&15)
  const int logical = (blockIdx.x & 7) * 96 + (blockIdx.x >> 3);  // 768%8==0
  const int qt = logical & 3, bh = logical >> 2;
  const int b = bh / NHEAD, h = bh % NHEAD;
  const int t = threadIdx.x;
  const int lane = t & 63, w = t >> 6;
  const int g = lane >> 4, lc = lane & 15;
  const int qrow = qt * 64 + w * 16 + lc;

  bf16x8 qf[2];
#pragma unroll
  for (int kk = 0; kk < 2; ++kk)
    qf[kk] = *(const bf16x8*)(Qb + ((size_t)bh * NQ + qrow) * 64 + kk * 32 + g * 8);

  const f32x4 z4 = {0.f, 0.f, 0.f, 0.f};
  f32x4 oacc[4];
#pragma unroll
  for (int df = 0; df < 4; ++df) oacc[df] = z4;
  float mrun = -1e30f, lrun = 0.f;

  const int r0 = t >> 3, c0 = t & 7;
  const int d0 = t >> 4, cv = t & 15;
  const int pbase = 32 * (cv >> 2) + 16 * (cv & 1) + 4 * ((cv >> 1) & 1);
  const int ch0 = pbase >> 3, of0 = pbase & 7;
  const int ch1 = (pbase + 8) >> 3;

  u16x8 rk[4], rv[4];
#define LOAD_TILE(KT)                                                                        \
  do {                                                                                       \
    const int kvb = (KT) * 128;                                                              \
    _Pragma("unroll")                                                                        \
    for (int pp = 0; pp < 4; ++pp)                                                           \
      rk[pp] = *(const u16x8*)(Kb + ((size_t)bh * NKV + kvb + pp * 32 + r0) * 64 + c0 * 8);  \
    _Pragma("unroll")                                                                        \
    for (int pp = 0; pp < 4; ++pp)                                                           \
      rv[pp] = *(const u16x8*)(Vtb + ((size_t)bh * 64 + pp * 16 + d0) * NKV + kvb + cv * 8); \
  } while (0)

  LOAD_TILE(0);

  for (int kt = 0; kt < 32; ++kt) {
    __syncthreads();
#pragma unroll
    for (int pp = 0; pp < 4; ++pp) {
      int row = pp * 32 + r0;
      *(u16x8*)&Ks[row * 64 + ((c0 ^ (row & 7)) << 3)] = rk[pp];
    }
#pragma unroll
    for (int pp = 0; pp < 4; ++pp) {
      int d = pp * 16 + d0;
      u16x4 lo = __builtin_shufflevector(rv[pp], rv[pp], 0, 1, 2, 3);
      u16x4 hi = __builtin_shufflevector(rv[pp], rv[pp], 4, 5, 6, 7);
      *(u16x4*)&Vts[d * 128 + ((ch0 ^ (d & 15)) << 3) + of0] = lo;
      *(u16x4*)&Vts[d * 128 + ((ch1 ^ (d & 15)) << 3) + of0] = hi;
    }
    if (kt + 1 < 32) LOAD_TILE(kt + 1);
    __syncthreads();

    f32x4 s[8];
#pragma unroll
    for (int c = 0; c < 8; ++c) s[c] = z4;
    __builtin_amdgcn_s_setprio(1);   // T5: favor matrix pipe during QK^T
#pragma unroll
    for (int kk = 0; kk < 2; ++kk)
#pragma unroll
      for (int c = 0; c < 8; ++c) {
        int row = c * 16 + lc;
        bf16x8 kf = *(const bf16x8*)&Ks[row * 64 + (((kk * 4 + g) ^ (row & 7)) << 3)];
        s[c] = __builtin_amdgcn_mfma_f32_16x16x32_bf16(kf, qf[kk], s[c], 0, 0, 0);
      }
    __builtin_amdgcn_s_setprio(0);

    float mx = s[0][0];
#pragma unroll
    for (int c = 0; c < 8; ++c)
#pragma unroll
      for (int r = 0; r < 4; ++r) mx = fmaxf(mx, s[c][r]);
    mx = fmaxf(mx, __shfl_xor(mx, 16));
    mx = fmaxf(mx, __shfl_xor(mx, 32));
    // T13 defer-max: skip rescale when max growth <= 8 (P bounded by e^8)
    if (!__all(mx - mrun <= 8.f)) {
      float nm = fmaxf(mrun, mx);
      float al = __expf(mrun - nm);
      mrun = nm;
      lrun *= al;
#pragma unroll
      for (int df = 0; df < 4; ++df)
#pragma unroll
        for (int r = 0; r < 4; ++r) oacc[df][r] *= al;
    }
    float ls = 0.f;
#pragma unroll
    for (int c = 0; c < 8; ++c)
#pragma unroll
      for (int r = 0; r < 4; ++r) {
        float p = __expf(s[c][r] - mrun);
        s[c][r] = p;
        ls += p;
      }
    ls += __shfl_xor(ls, 16);
    ls += __shfl_xor(ls, 32);
    lrun += ls;

    uint32_t pk[8][2];
#pragma unroll
    for (int c = 0; c < 8; ++c)
#pragma unroll
      for (int w2 = 0; w2 < 2; ++w2)
        pk[c][w2] = cvtpk(s[c][2 * w2], s[c][2 * w2 + 1]);

    __builtin_amdgcn_s_setprio(1);   // T5: favor matrix pipe during PV
#pragma unroll
    for (int kb = 0; kb < 4; ++kb) {
      u32x4 pw = {pk[2 * kb][0], pk[2 * kb][1], pk[2 * kb + 1][0], pk[2 * kb + 1][1]};
      bf16x8 pa = __builtin_bit_cast(bf16x8, pw);
#pragma unroll
      for (int df = 0; df < 4; ++df) {
        int row = df * 16 + lc;
        bf16x8 vf = *(const bf16x8*)&Vts[row * 128 + (((kb * 4 + g) ^ (row & 15)) << 3)];
        oacc[df] = __builtin_amdgcn_mfma_f32_16x16x32_bf16(vf, pa, oacc[df], 0, 0, 0);
      }
    }
    __builtin_amdgcn_s_setprio(0);
  }
#undef LOAD_TILE

  float inv = 1.0f / lrun;
#pragma unroll
  for (int df = 0; df < 4; ++df) {
    us4 wv{f2bf(oacc[df][0] * inv), f2bf(oacc[df][1] * inv),
           f2bf(oacc[df][2] * inv), f2bf(oacc[df][3] * inv)};
    *(us4*)&Ob[((size_t)b * NQ + qrow) * DIMF + h * 64 + df * 16 + g * 4] = wv;
  }
}

// ---------------- launch ----------------------------------------------------
extern "C" void kernel_launch(void* const* d_in, const int* in_sizes, int n_in,
                              void* d_out, int out_size, void* d_ws, size_t ws_size,
                              hipStream_t stream) {
  const float* x      = (const float*)d_in[0];
  const float* ctx    = (const float*)d_in[1];
  const float* rope_q = (const float*)d_in[2];
  const float* rope_k = (const float*)d_in[3];
  const float* Wq     = (const float*)d_in[4];
  const float* Wk     = (const float*)d_in[5];
  const float* Wv     = (const float*)d_in[6];
  const float* Wo     = (const float*)d_in[7];

  char* ws = (char*)d_ws;
  const size_t SZ_CTXB = (size_t)NB * NKV * DIMF * 2;
  const size_t SZ_XB   = (size_t)NB * NQ * DIMF * 2;
  const size_t SZ_WT   = (size_t)DIMF * DIMF * 2;
  unsigned short* ctxb = (unsigned short*)(ws);
  unsigned short* ob   = (unsigned short*)(ws);                       // alias ctxb (dead after kvgemm)
  unsigned short* xb   = (unsigned short*)(ws + SZ_CTXB);
  unsigned short* wkt  = (unsigned short*)(ws + SZ_CTXB + SZ_XB);           // wkt||wvt = wkvt[1536][768]
  unsigned short* wvt  = (unsigned short*)(ws + SZ_CTXB + SZ_XB + SZ_WT);
  unsigned short* wqt  = (unsigned short*)(ws + SZ_CTXB + SZ_XB + 2 * SZ_WT);
  unsigned short* wot  = (unsigned short*)(ws + SZ_CTXB + SZ_XB + 3 * SZ_WT);
  unsigned short* kb   = (unsigned short*)(ws + SZ_CTXB + SZ_XB + 4 * SZ_WT);
  unsigned short* vtb  = (unsigned short*)(ws + SZ_CTXB + SZ_XB + 4 * SZ_WT + SZ_CTXB);
  unsigned short* qb   = (unsigned short*)(ws + SZ_CTXB + SZ_XB + 4 * SZ_WT + 2 * SZ_CTXB);

  cvt_kernel<<<dim3(2048), dim3(256), 0, stream>>>(ctx, ctxb, NB * NKV * DIMF);
  cvt_kernel<<<dim3(1024), dim3(256), 0, stream>>>(x, xb, NB * NQ * DIMF);
  twt_kernel<<<dim3(24, 24, 4), dim3(32, 8), 0, stream>>>(Wk, Wv, Wq, Wo, wkt, wvt, wqt, wot);

  kv8_kernel<<<dim3(1536), dim3(512), 131072, stream>>>(ctxb, wkt, kb, vtb, rope_k);
  gemm_kernel<2><<<dim3(32, 6), dim3(256), 0, stream>>>(xb, wqt, qb, rope_q);

  attn_kernel<<<dim3(768), dim3(256), 0, stream>>>(qb, kb, vtb, ob);

  gemm_kernel<3><<<dim3(32, 6), dim3(256), 0, stream>>>(ob, wot, d_out, nullptr);
}

// Round 22
// 376.664 us; speedup vs baseline: 1.0715x; 1.0018x over previous
//
#include <hip/hip_runtime.h>
#include <stdint.h>

// ---------------------------------------------------------------------------
// CrossAttentionRope: x(16,256,768), ctx(16,4096,768) f32 -> out(16,256,768) f32
// R22: R21 (best, 377.4us) + attn barrier fix: __syncthreads() drains vmcnt(0),
//      killing the K/V prefetch every tile (~900cy stall x32). Replaced with
//      {s_waitcnt lgkmcnt(0); fence; s_barrier; fence} (kv8's R17-proven
//      pattern) — global prefetch stays in flight across barriers; rk/rv are
//      guarded by the compiler's automatic counted vmcnt before ds_write use.
//      Everything else byte-identical R21.
// ---------------------------------------------------------------------------

typedef __bf16 bf16x8 __attribute__((ext_vector_type(8)));
typedef unsigned short u16x8 __attribute__((ext_vector_type(8)));
typedef unsigned short u16x4 __attribute__((ext_vector_type(4)));
typedef uint32_t u32x4 __attribute__((ext_vector_type(4)));
typedef float f32x4 __attribute__((ext_vector_type(4)));

#define DIMF 768
#define NHEAD 12
#define NKV 4096
#define NQ 256
#define NB 16

struct alignas(8) us4 { unsigned short x, y, z, w; };

__device__ __forceinline__ unsigned short f2bf(float x) {
  uint32_t u = __float_as_uint(x);
  u += 0x7fffu + ((u >> 16) & 1u);   // round-to-nearest-even
  return (unsigned short)(u >> 16);
}

__device__ __forceinline__ uint32_t cvtpk(float a, float b) {
  uint32_t r;
  asm("v_cvt_pk_bf16_f32 %0, %1, %2" : "=v"(r) : "v"(a), "v"(b));
  return r;
}

__device__ __forceinline__ void gld_lds16(const unsigned short* g, unsigned short* l) {
  __builtin_amdgcn_global_load_lds(
      (const __attribute__((address_space(1))) uint32_t*)(uintptr_t)g,
      (__attribute__((address_space(3))) uint32_t*)(uintptr_t)l, 16, 0, 0);
}

// lgkm-only barrier (no vmcnt drain): per-wave LDS ops complete, then sync.
__device__ __forceinline__ void lds_barrier() {
  asm volatile("s_waitcnt lgkmcnt(0)" ::: "memory");
  asm volatile("" ::: "memory");
  __builtin_amdgcn_s_barrier();
  asm volatile("" ::: "memory");
}

// ---------------- convert f32 -> bf16 (vectorized, grid-stride) ------------
__global__ void cvt_kernel(const float* __restrict__ in, unsigned short* __restrict__ out, int n) {
  int stride = gridDim.x * blockDim.x * 4;
  for (int i = (blockIdx.x * blockDim.x + threadIdx.x) * 4; i < n; i += stride) {
    float4 v = *(const float4*)(in + i);
    us4 o{f2bf(v.x), f2bf(v.y), f2bf(v.z), f2bf(v.w)};
    *(us4*)(out + i) = o;
  }
}

// ---------------- weight transpose + cvt: Wt[n][k] = W[k][n] ---------------
__global__ void twt_kernel(const float* __restrict__ W0, const float* __restrict__ W1,
                           const float* __restrict__ W2, const float* __restrict__ W3,
                           unsigned short* __restrict__ O0, unsigned short* __restrict__ O1,
                           unsigned short* __restrict__ O2, unsigned short* __restrict__ O3) {
  const float* W; unsigned short* O;
  switch (blockIdx.z) {
    case 0: W = W0; O = O0; break;
    case 1: W = W1; O = O1; break;
    case 2: W = W2; O = O2; break;
    default: W = W3; O = O3; break;
  }
  __shared__ float t[32][33];
  int x0 = blockIdx.x * 32, y0 = blockIdx.y * 32;
  int tx = threadIdx.x, ty = threadIdx.y;
#pragma unroll
  for (int j = 0; j < 4; ++j)
    t[ty + 8 * j][tx] = W[(size_t)(y0 + ty + 8 * j) * DIMF + x0 + tx];
  __syncthreads();
#pragma unroll
  for (int j = 0; j < 4; ++j)
    O[(size_t)(x0 + ty + 8 * j) * DIMF + y0 + tx] = f2bf(t[tx][ty + 8 * j]);
}

// ---------------- merged KV GEMM: 256x256, 8-phase per-phase-vmcnt ----------
// (R17-proven.) Grid 1536 (256 rows x 6 cols), col-fast XCD swizzle.
// 512 thr / 8 waves; per-wave C = 128x64 interleaved.
__launch_bounds__(512, 1)
__global__ void kv8_kernel(const unsigned short* __restrict__ A,
                           const unsigned short* __restrict__ Bkv,
                           unsigned short* __restrict__ Ko,
                           unsigned short* __restrict__ Vt,
                           const float* __restrict__ rope) {
  extern __shared__ unsigned short smem[];   // 65536 shorts = 128KB
  const int t = threadIdx.x;
  const int lane = t & 63, wid = t >> 6;
  const int g = lane >> 4, lc = lane & 15;
  const int wr = wid >> 2, wc = wid & 3;

  const int swz = (blockIdx.x & 7) * 192 + (blockIdx.x >> 3);  // 1536%8==0
  const int rowBase = (swz / 6) * 256;
  const int colBase = (swz % 6) * 256;

  f32x4 acc[8][4];
#pragma unroll
  for (int m = 0; m < 8; ++m)
#pragma unroll
    for (int n = 0; n < 4; ++n)
#pragma unroll
      for (int r = 0; r < 4; ++r) acc[m][n][r] = 0.f;

  const int sr = lane >> 3;
  const int sc = (lane & 7) ^ sr;
  const unsigned short* Abase0 = A + (size_t)(rowBase + wid * 16 + sr) * DIMF + sc * 8;
  const unsigned short* Bbase0 = Bkv + (size_t)(colBase + wid * 16 + sr) * DIMF + sc * 8;

#define STAGE_A(T, h)                                                              \
  do {                                                                             \
    unsigned short* _lb = smem + (((T) & 1) * 2 + (h)) * 8192;                     \
    const unsigned short* _gb = Abase0 + (size_t)(h) * 128 * DIMF + (T) * 64;      \
    gld_lds16(_gb, _lb + (wid * 16) * 64);                                         \
    gld_lds16(_gb + (size_t)8 * DIMF, _lb + (wid * 16 + 8) * 64);                  \
  } while (0)
#define STAGE_B(T, h)                                                              \
  do {                                                                             \
    unsigned short* _lb = smem + 32768 + (((T) & 1) * 2 + (h)) * 8192;             \
    const unsigned short* _gb = Bbase0 + (size_t)(h) * 128 * DIMF + (T) * 64;      \
    gld_lds16(_gb, _lb + (wid * 16) * 64);                                         \
    gld_lds16(_gb + (size_t)8 * DIMF, _lb + (wid * 16 + 8) * 64);                  \
  } while (0)

  // prologue: T0 complete + T1's tops (order defines the FIFO wait arithmetic)
  STAGE_A(0, 0); STAGE_B(0, 0); STAGE_B(0, 1); STAGE_A(0, 1);
  STAGE_A(1, 0); STAGE_B(1, 0);

  bf16x8 af[4][2], bfr[2][2];

  for (int T = 0; T < 12; ++T) {
    const int dbuf = T & 1;
#pragma unroll
    for (int q = 0; q < 4; ++q) {
      const int ah = q >> 1, bh = q & 1;
      if (q == 0) {
        if (T < 11) asm volatile("s_waitcnt vmcnt(8)" ::: "memory");
        else        asm volatile("s_waitcnt vmcnt(4)" ::: "memory");
      } else if (q == 1) {
        if (T < 11) asm volatile("s_waitcnt vmcnt(8)" ::: "memory");
        else        asm volatile("s_waitcnt vmcnt(2)" ::: "memory");
      } else if (q == 2) {
        if (T < 11) asm volatile("s_waitcnt vmcnt(8)" ::: "memory");
        else        asm volatile("s_waitcnt vmcnt(0)" ::: "memory");
      }
      asm volatile("" ::: "memory");
      __builtin_amdgcn_s_barrier();     // all waves' needed loads visible
      asm volatile("" ::: "memory");

      const unsigned short* Ab = smem + (dbuf * 2 + ah) * 8192;
      const unsigned short* Bb = smem + 32768 + (dbuf * 2 + bh) * 8192;
      if ((q & 1) == 0) {              // A-half frags reused across 2 phases
#pragma unroll
        for (int mp = 0; mp < 4; ++mp)
#pragma unroll
          for (int kk = 0; kk < 2; ++kk) {
            int row = mp * 32 + wr * 16 + lc;
            af[mp][kk] = *(const bf16x8*)&Ab[row * 64 + (((kk * 4 + g) ^ (row & 7)) << 3)];
          }
      }
#pragma unroll
      for (int np = 0; np < 2; ++np)
#pragma unroll
        for (int kk = 0; kk < 2; ++kk) {
          int row = np * 64 + wc * 16 + lc;
          bfr[np][kk] = *(const bf16x8*)&Bb[row * 64 + (((kk * 4 + g) ^ (row & 7)) << 3)];
        }
      // stage issue (slot's readers retired before this phase's barrier):
      if (q == 0)      { if (T + 1 < 12) STAGE_B(T + 1, 1); }   // T+1:B-bot
      else if (q == 1) { if (T + 1 < 12) STAGE_A(T + 1, 1); }   // T+1:A-bot
      else if (q == 2) { if (T + 2 < 12) STAGE_A(T + 2, 0); }   // T+2:A-top
      else             { if (T + 2 < 12) STAGE_B(T + 2, 0); }   // T+2:B-top
      asm volatile("s_waitcnt lgkmcnt(0)" ::: "memory");
      __builtin_amdgcn_sched_barrier(0);   // rule #18
      __builtin_amdgcn_s_setprio(1);
#pragma unroll
      for (int mp = 0; mp < 4; ++mp)
#pragma unroll
        for (int np = 0; np < 2; ++np)
#pragma unroll
          for (int kk = 0; kk < 2; ++kk)
            acc[4 * ah + mp][2 * bh + np] = __builtin_amdgcn_mfma_f32_16x16x32_bf16(
                af[mp][kk], bfr[np][kk], acc[4 * ah + mp][2 * bh + np], 0, 0, 0);
      __builtin_amdgcn_s_setprio(0);
    }
  }
#undef STAGE_A
#undef STAGE_B

  // ---- epilogue (C/D: col=lc, row=g*4+r — proven); block-uniform branch ----
  if (colBase < 768) {   // K output + rope
#pragma unroll
    for (int m = 0; m < 8; ++m)
#pragma unroll
      for (int n = 0; n < 4; ++n)
#pragma unroll
        for (int r = 0; r < 4; ++r) {
          int p = rowBase + m * 32 + wr * 16 + g * 4 + r;
          int f = colBase + n * 64 + wc * 16 + lc;
          int d = f & 63, h = f >> 6;
          float v = acc[m][n][r];
          float vo = __shfl_xor(v, 1);
          int b = p >> 12, nkv = p & 4095;
          float sn = rope[nkv * 128 + d], cs = rope[nkv * 128 + 64 + d];
          float o = (d & 1) ? fmaf(vo, sn, v * cs) : fmaf(-vo, sn, v * cs);
          Ko[((size_t)(b * NHEAD + h) * NKV + nkv) * 64 + d] = f2bf(o);
        }
  } else {               // V output, transposed [b][h][d][nkv]
#pragma unroll
    for (int m = 0; m < 8; ++m)
#pragma unroll
      for (int n = 0; n < 4; ++n) {
        int p0 = rowBase + m * 32 + wr * 16 + g * 4;
        int b = p0 >> 12, nkv0 = p0 & 4095;
        int f = (colBase - 768) + n * 64 + wc * 16 + lc;
        int d = f & 63, h = f >> 6;
        us4 wv{f2bf(acc[m][n][0]), f2bf(acc[m][n][1]), f2bf(acc[m][n][2]), f2bf(acc[m][n][3])};
        *(us4*)&Vt[((size_t)(b * NHEAD + h) * 64 + d) * NKV + nkv0] = wv;
      }
  }
}

// ---------------- GEMM (R5/R8-proven reg-staged): Q-proj / O-proj -----------
// MODE 2: Q-proj (+rope_q, *0.125) -> Q [b][h][nq][64] bf16  [2D grid]
// MODE 3: O-proj -> out f32 [p][768]                          [2D grid]
template <int MODE>
__launch_bounds__(256, 2)
__global__ void gemm_kernel(const unsigned short* __restrict__ A,
                            const unsigned short* __restrict__ Bt,
                            void* __restrict__ outp,
                            const float* __restrict__ rope) {
  __shared__ unsigned short As[128 * 64];
  __shared__ unsigned short Bs[128 * 64];
  const int t = threadIdx.x;
  const int lane = t & 63, wid = t >> 6;
  const int g = lane >> 4, lc = lane & 15;
  const int wr = wid >> 1, wc = wid & 1;
  const int rowBase = blockIdx.x * 128, colBase = blockIdx.y * 128;

  const f32x4 z4 = {0.f, 0.f, 0.f, 0.f};
  f32x4 acc[4][4];
#pragma unroll
  for (int m = 0; m < 4; ++m)
#pragma unroll
    for (int n = 0; n < 4; ++n) acc[m][n] = z4;

  const int r0 = t >> 3;
  const int c0 = t & 7;

  bf16x8 ra[4], rbx[4];
#pragma unroll
  for (int pp = 0; pp < 4; ++pp) {
    int row = pp * 32 + r0;
    ra[pp] = *(const bf16x8*)(A + (size_t)(rowBase + row) * DIMF + c0 * 8);
    rbx[pp] = *(const bf16x8*)(Bt + (size_t)(colBase + row) * DIMF + c0 * 8);
  }

  for (int kb = 0; kb < 12; ++kb) {
    __syncthreads();
#pragma unroll
    for (int pp = 0; pp < 4; ++pp) {
      int row = pp * 32 + r0;
      int ph = ((c0 ^ (row & 7)) << 3);
      *(bf16x8*)&As[row * 64 + ph] = ra[pp];
      *(bf16x8*)&Bs[row * 64 + ph] = rbx[pp];
    }
    __syncthreads();
    if (kb + 1 < 12) {
      int kn = (kb + 1) * 64;
#pragma unroll
      for (int pp = 0; pp < 4; ++pp) {
        int row = pp * 32 + r0;
        ra[pp] = *(const bf16x8*)(A + (size_t)(rowBase + row) * DIMF + kn + c0 * 8);
        rbx[pp] = *(const bf16x8*)(Bt + (size_t)(colBase + row) * DIMF + kn + c0 * 8);
      }
    }
#pragma unroll
    for (int kk = 0; kk < 2; ++kk) {
      bf16x8 af[4], bfr[4];
#pragma unroll
      for (int m = 0; m < 4; ++m) {
        int row = wr * 64 + m * 16 + lc;
        int ch = kk * 4 + g;
        af[m] = *(const bf16x8*)&As[row * 64 + (((ch ^ (row & 7))) << 3)];
      }
#pragma unroll
      for (int n = 0; n < 4; ++n) {
        int row = wc * 64 + n * 16 + lc;
        int ch = kk * 4 + g;
        bfr[n] = *(const bf16x8*)&Bs[row * 64 + (((ch ^ (row & 7))) << 3)];
      }
#pragma unroll
      for (int m = 0; m < 4; ++m)
#pragma unroll
        for (int n = 0; n < 4; ++n)
          acc[m][n] = __builtin_amdgcn_mfma_f32_16x16x32_bf16(af[m], bfr[n], acc[m][n], 0, 0, 0);
    }
  }

  if (MODE == 2) {
    unsigned short* Ko = (unsigned short*)outp;
#pragma unroll
    for (int m = 0; m < 4; ++m)
#pragma unroll
      for (int n = 0; n < 4; ++n)
#pragma unroll
        for (int r = 0; r < 4; ++r) {
          int p = rowBase + wr * 64 + m * 16 + g * 4 + r;
          int f = colBase + wc * 64 + n * 16 + lc;
          int d = f & 63, h = f >> 6;
          float v = acc[m][n][r];
          float vo = __shfl_xor(v, 1);
          int b = p >> 8, nq = p & 255;
          float sn = rope[nq * 128 + d], cs = rope[nq * 128 + 64 + d];
          float o = (d & 1) ? fmaf(vo, sn, v * cs) : fmaf(-vo, sn, v * cs);
          Ko[((size_t)(b * NHEAD + h) * NQ + nq) * 64 + d] = f2bf(o * 0.125f);
        }
  } else {
    float* Co = (float*)outp;
#pragma unroll
    for (int m = 0; m < 4; ++m)
#pragma unroll
      for (int n = 0; n < 4; ++n)
#pragma unroll
        for (int r = 0; r < 4; ++r) {
          int p = rowBase + wr * 64 + m * 16 + g * 4 + r;
          int f = colBase + wc * 64 + n * 16 + lc;
          Co[(size_t)p * DIMF + f] = acc[m][n][r];
        }
  }
}

// ---------------- flash attention (R21 + lgkm-only barriers) ----------------
__launch_bounds__(256, 3)
__global__ void attn_kernel(const unsigned short* __restrict__ Qb,
                            const unsigned short* __restrict__ Kb,
                            const unsigned short* __restrict__ Vtb,
                            unsigned short* __restrict__ Ob) {
  __shared__ unsigned short Ks[128 * 64];    // [kv][d]  16KB, chunk ^= (kv&7)
  __shared__ unsigned short Vts[64 * 128];   // [d][kv'] 16KB, chunk ^= (d&15)
  const int logical = (blockIdx.x & 7) * 96 + (blockIdx.x >> 3);  // 768%8==0
  const int qt = logical & 3, bh = logical >> 2;
  const int b = bh / NHEAD, h = bh % NHEAD;
  const int t = threadIdx.x;
  const int lane = t & 63, w = t >> 6;
  const int g = lane >> 4, lc = lane & 15;
  const int qrow = qt * 64 + w * 16 + lc;

  bf16x8 qf[2];
#pragma unroll
  for (int kk = 0; kk < 2; ++kk)
    qf[kk] = *(const bf16x8*)(Qb + ((size_t)bh * NQ + qrow) * 64 + kk * 32 + g * 8);

  const f32x4 z4 = {0.f, 0.f, 0.f, 0.f};
  f32x4 oacc[4];
#pragma unroll
  for (int df = 0; df < 4; ++df) oacc[df] = z4;
  float mrun = -1e30f, lrun = 0.f;

  const int r0 = t >> 3, c0 = t & 7;
  const int d0 = t >> 4, cv = t & 15;
  const int pbase = 32 * (cv >> 2) + 16 * (cv & 1) + 4 * ((cv >> 1) & 1);
  const int ch0 = pbase >> 3, of0 = pbase & 7;
  const int ch1 = (pbase + 8) >> 3;

  u16x8 rk[4], rv[4];
#define LOAD_TILE(KT)                                                                        \
  do {                                                                                       \
    const int kvb = (KT) * 128;                                                              \
    _Pragma("unroll")                                                                        \
    for (int pp = 0; pp < 4; ++pp)                                                           \
      rk[pp] = *(const u16x8*)(Kb + ((size_t)bh * NKV + kvb + pp * 32 + r0) * 64 + c0 * 8);  \
    _Pragma("unroll")                                                                        \
    for (int pp = 0; pp < 4; ++pp)                                                           \
      rv[pp] = *(const u16x8*)(Vtb + ((size_t)bh * 64 + pp * 16 + d0) * NKV + kvb + cv * 8); \
  } while (0)

  LOAD_TILE(0);

  for (int kt = 0; kt < 32; ++kt) {
    lds_barrier();   // prev tile's LDS reads done (lgkm only — no vmcnt drain)
#pragma unroll
    for (int pp = 0; pp < 4; ++pp) {
      int row = pp * 32 + r0;
      *(u16x8*)&Ks[row * 64 + ((c0 ^ (row & 7)) << 3)] = rk[pp];
    }
#pragma unroll
    for (int pp = 0; pp < 4; ++pp) {
      int d = pp * 16 + d0;
      u16x4 lo = __builtin_shufflevector(rv[pp], rv[pp], 0, 1, 2, 3);
      u16x4 hi = __builtin_shufflevector(rv[pp], rv[pp], 4, 5, 6, 7);
      *(u16x4*)&Vts[d * 128 + ((ch0 ^ (d & 15)) << 3) + of0] = lo;
      *(u16x4*)&Vts[d * 128 + ((ch1 ^ (d & 15)) << 3) + of0] = hi;
    }
    if (kt + 1 < 32) LOAD_TILE(kt + 1);   // prefetch; stays in flight across barrier
    lds_barrier();   // staging visible (lgkm only — prefetch NOT drained)

    f32x4 s[8];
#pragma unroll
    for (int c = 0; c < 8; ++c) s[c] = z4;
    __builtin_amdgcn_s_setprio(1);   // T5: favor matrix pipe during QK^T
#pragma unroll
    for (int kk = 0; kk < 2; ++kk)
#pragma unroll
      for (int c = 0; c < 8; ++c) {
        int row = c * 16 + lc;
        bf16x8 kf = *(const bf16x8*)&Ks[row * 64 + (((kk * 4 + g) ^ (row & 7)) << 3)];
        s[c] = __builtin_amdgcn_mfma_f32_16x16x32_bf16(kf, qf[kk], s[c], 0, 0, 0);
      }
    __builtin_amdgcn_s_setprio(0);

    float mx = s[0][0];
#pragma unroll
    for (int c = 0; c < 8; ++c)
#pragma unroll
      for (int r = 0; r < 4; ++r) mx = fmaxf(mx, s[c][r]);
    mx = fmaxf(mx, __shfl_xor(mx, 16));
    mx = fmaxf(mx, __shfl_xor(mx, 32));
    // T13 defer-max: skip rescale when max growth <= 8 (P bounded by e^8)
    if (!__all(mx - mrun <= 8.f)) {
      float nm = fmaxf(mrun, mx);
      float al = __expf(mrun - nm);
      mrun = nm;
      lrun *= al;
#pragma unroll
      for (int df = 0; df < 4; ++df)
#pragma unroll
        for (int r = 0; r < 4; ++r) oacc[df][r] *= al;
    }
    float ls = 0.f;
#pragma unroll
    for (int c = 0; c < 8; ++c)
#pragma unroll
      for (int r = 0; r < 4; ++r) {
        float p = __expf(s[c][r] - mrun);
        s[c][r] = p;
        ls += p;
      }
    ls += __shfl_xor(ls, 16);
    ls += __shfl_xor(ls, 32);
    lrun += ls;

    uint32_t pk[8][2];
#pragma unroll
    for (int c = 0; c < 8; ++c)
#pragma unroll
      for (int w2 = 0; w2 < 2; ++w2)
        pk[c][w2] = cvtpk(s[c][2 * w2], s[c][2 * w2 + 1]);

    __builtin_amdgcn_s_setprio(1);   // T5: favor matrix pipe during PV
#pragma unroll
    for (int kb = 0; kb < 4; ++kb) {
      u32x4 pw = {pk[2 * kb][0], pk[2 * kb][1], pk[2 * kb + 1][0], pk[2 * kb + 1][1]};
      bf16x8 pa = __builtin_bit_cast(bf16x8, pw);
#pragma unroll
      for (int df = 0; df < 4; ++df) {
        int row = df * 16 + lc;
        bf16x8 vf = *(const bf16x8*)&Vts[row * 128 + (((kb * 4 + g) ^ (row & 15)) << 3)];
        oacc[df] = __builtin_amdgcn_mfma_f32_16x16x32_bf16(vf, pa, oacc[df], 0, 0, 0);
      }
    }
    __builtin_amdgcn_s_setprio(0);
  }
#undef LOAD_TILE

  float inv = 1.0f / lrun;
#pragma unroll
  for (int df = 0; df < 4; ++df) {
    us4 wv{f2bf(oacc[df][0] * inv), f2bf(oacc[df][1] * inv),
           f2bf(oacc[df][2] * inv), f2bf(oacc[df][3] * inv)};
    *(us4*)&Ob[((size_t)b * NQ + qrow) * DIMF + h * 64 + df * 16 + g * 4] = wv;
  }
}

// ---------------- launch ----------------------------------------------------
extern "C" void kernel_launch(void* const* d_in, const int* in_sizes, int n_in,
                              void* d_out, int out_size, void* d_ws, size_t ws_size,
                              hipStream_t stream) {
  const float* x      = (const float*)d_in[0];
  const float* ctx    = (const float*)d_in[1];
  const float* rope_q = (const float*)d_in[2];
  const float* rope_k = (const float*)d_in[3];
  const float* Wq     = (const float*)d_in[4];
  const float* Wk     = (const float*)d_in[5];
  const float* Wv     = (const float*)d_in[6];
  const float* Wo     = (const float*)d_in[7];

  char* ws = (char*)d_ws;
  const size_t SZ_CTXB = (size_t)NB * NKV * DIMF * 2;
  const size_t SZ_XB   = (size_t)NB * NQ * DIMF * 2;
  const size_t SZ_WT   = (size_t)DIMF * DIMF * 2;
  unsigned short* ctxb = (unsigned short*)(ws);
  unsigned short* ob   = (unsigned short*)(ws);                       // alias ctxb (dead after kvgemm)
  unsigned short* xb   = (unsigned short*)(ws + SZ_CTXB);
  unsigned short* wkt  = (unsigned short*)(ws + SZ_CTXB + SZ_XB);           // wkt||wvt = wkvt[1536][768]
  unsigned short* wvt  = (unsigned short*)(ws + SZ_CTXB + SZ_XB + SZ_WT);
  unsigned short* wqt  = (unsigned short*)(ws + SZ_CTXB + SZ_XB + 2 * SZ_WT);
  unsigned short* wot  = (unsigned short*)(ws + SZ_CTXB + SZ_XB + 3 * SZ_WT);
  unsigned short* kb   = (unsigned short*)(ws + SZ_CTXB + SZ_XB + 4 * SZ_WT);
  unsigned short* vtb  = (unsigned short*)(ws + SZ_CTXB + SZ_XB + 4 * SZ_WT + SZ_CTXB);
  unsigned short* qb   = (unsigned short*)(ws + SZ_CTXB + SZ_XB + 4 * SZ_WT + 2 * SZ_CTXB);

  cvt_kernel<<<dim3(2048), dim3(256), 0, stream>>>(ctx, ctxb, NB * NKV * DIMF);
  cvt_kernel<<<dim3(1024), dim3(256), 0, stream>>>(x, xb, NB * NQ * DIMF);
  twt_kernel<<<dim3(24, 24, 4), dim3(32, 8), 0, stream>>>(Wk, Wv, Wq, Wo, wkt, wvt, wqt, wot);

  kv8_kernel<<<dim3(1536), dim3(512), 131072, stream>>>(ctxb, wkt, kb, vtb, rope_k);
  gemm_kernel<2><<<dim3(32, 6), dim3(256), 0, stream>>>(xb, wqt, qb, rope_q);

  attn_kernel<<<dim3(768), dim3(256), 0, stream>>>(qb, kb, vtb, ob);

  gemm_kernel<3><<<dim3(32, 6), dim3(256), 0, stream>>>(ob, wot, d_out, nullptr);
}

// Round 24
// 366.211 us; speedup vs baseline: 1.1021x; 1.0285x over previous
//
#include <hip/hip_runtime.h>
#include <stdint.h>

// ---------------------------------------------------------------------------
// CrossAttentionRope: x(16,256,768), ctx(16,4096,768) f32 -> out(16,256,768) f32
// R24: R23's rope-staging OOB fixed — stage base is (rowBase & 4095)*128
//      (rope_k has 4096 rows; p's row-within-batch is p&4095; rowBase%256==0
//      and 4096%256==0 so the 256-row tile never crosses a batch boundary).
//      Everything else byte-identical R23 (= R22 + K-epilogue rope staging).
// ---------------------------------------------------------------------------

typedef __bf16 bf16x8 __attribute__((ext_vector_type(8)));
typedef unsigned short u16x8 __attribute__((ext_vector_type(8)));
typedef unsigned short u16x4 __attribute__((ext_vector_type(4)));
typedef uint32_t u32x4 __attribute__((ext_vector_type(4)));
typedef float f32x4 __attribute__((ext_vector_type(4)));

#define DIMF 768
#define NHEAD 12
#define NKV 4096
#define NQ 256
#define NB 16

struct alignas(8) us4 { unsigned short x, y, z, w; };

__device__ __forceinline__ unsigned short f2bf(float x) {
  uint32_t u = __float_as_uint(x);
  u += 0x7fffu + ((u >> 16) & 1u);   // round-to-nearest-even
  return (unsigned short)(u >> 16);
}

__device__ __forceinline__ uint32_t cvtpk(float a, float b) {
  uint32_t r;
  asm("v_cvt_pk_bf16_f32 %0, %1, %2" : "=v"(r) : "v"(a), "v"(b));
  return r;
}

__device__ __forceinline__ void gld_lds16(const unsigned short* g, unsigned short* l) {
  __builtin_amdgcn_global_load_lds(
      (const __attribute__((address_space(1))) uint32_t*)(uintptr_t)g,
      (__attribute__((address_space(3))) uint32_t*)(uintptr_t)l, 16, 0, 0);
}

// lgkm-only barrier (no vmcnt drain): per-wave LDS ops complete, then sync.
__device__ __forceinline__ void lds_barrier() {
  asm volatile("s_waitcnt lgkmcnt(0)" ::: "memory");
  asm volatile("" ::: "memory");
  __builtin_amdgcn_s_barrier();
  asm volatile("" ::: "memory");
}

// ---------------- convert f32 -> bf16 (vectorized, grid-stride) ------------
__global__ void cvt_kernel(const float* __restrict__ in, unsigned short* __restrict__ out, int n) {
  int stride = gridDim.x * blockDim.x * 4;
  for (int i = (blockIdx.x * blockDim.x + threadIdx.x) * 4; i < n; i += stride) {
    float4 v = *(const float4*)(in + i);
    us4 o{f2bf(v.x), f2bf(v.y), f2bf(v.z), f2bf(v.w)};
    *(us4*)(out + i) = o;
  }
}

// ---------------- weight transpose + cvt: Wt[n][k] = W[k][n] ---------------
__global__ void twt_kernel(const float* __restrict__ W0, const float* __restrict__ W1,
                           const float* __restrict__ W2, const float* __restrict__ W3,
                           unsigned short* __restrict__ O0, unsigned short* __restrict__ O1,
                           unsigned short* __restrict__ O2, unsigned short* __restrict__ O3) {
  const float* W; unsigned short* O;
  switch (blockIdx.z) {
    case 0: W = W0; O = O0; break;
    case 1: W = W1; O = O1; break;
    case 2: W = W2; O = O2; break;
    default: W = W3; O = O3; break;
  }
  __shared__ float t[32][33];
  int x0 = blockIdx.x * 32, y0 = blockIdx.y * 32;
  int tx = threadIdx.x, ty = threadIdx.y;
#pragma unroll
  for (int j = 0; j < 4; ++j)
    t[ty + 8 * j][tx] = W[(size_t)(y0 + ty + 8 * j) * DIMF + x0 + tx];
  __syncthreads();
#pragma unroll
  for (int j = 0; j < 4; ++j)
    O[(size_t)(x0 + ty + 8 * j) * DIMF + y0 + tx] = f2bf(t[tx][ty + 8 * j]);
}

// ---------------- merged KV GEMM: 256x256, 8-phase per-phase-vmcnt ----------
// (R17-proven.) Grid 1536 (256 rows x 6 cols), col-fast XCD swizzle.
// 512 thr / 8 waves; per-wave C = 128x64 interleaved.
__launch_bounds__(512, 1)
__global__ void kv8_kernel(const unsigned short* __restrict__ A,
                           const unsigned short* __restrict__ Bkv,
                           unsigned short* __restrict__ Ko,
                           unsigned short* __restrict__ Vt,
                           const float* __restrict__ rope) {
  extern __shared__ unsigned short smem[];   // 65536 shorts = 128KB
  const int t = threadIdx.x;
  const int lane = t & 63, wid = t >> 6;
  const int g = lane >> 4, lc = lane & 15;
  const int wr = wid >> 2, wc = wid & 3;

  const int swz = (blockIdx.x & 7) * 192 + (blockIdx.x >> 3);  // 1536%8==0
  const int rowBase = (swz / 6) * 256;
  const int colBase = (swz % 6) * 256;

  f32x4 acc[8][4];
#pragma unroll
  for (int m = 0; m < 8; ++m)
#pragma unroll
    for (int n = 0; n < 4; ++n)
#pragma unroll
      for (int r = 0; r < 4; ++r) acc[m][n][r] = 0.f;

  const int sr = lane >> 3;
  const int sc = (lane & 7) ^ sr;
  const unsigned short* Abase0 = A + (size_t)(rowBase + wid * 16 + sr) * DIMF + sc * 8;
  const unsigned short* Bbase0 = Bkv + (size_t)(colBase + wid * 16 + sr) * DIMF + sc * 8;

#define STAGE_A(T, h)                                                              \
  do {                                                                             \
    unsigned short* _lb = smem + (((T) & 1) * 2 + (h)) * 8192;                     \
    const unsigned short* _gb = Abase0 + (size_t)(h) * 128 * DIMF + (T) * 64;      \
    gld_lds16(_gb, _lb + (wid * 16) * 64);                                         \
    gld_lds16(_gb + (size_t)8 * DIMF, _lb + (wid * 16 + 8) * 64);                  \
  } while (0)
#define STAGE_B(T, h)                                                              \
  do {                                                                             \
    unsigned short* _lb = smem + 32768 + (((T) & 1) * 2 + (h)) * 8192;             \
    const unsigned short* _gb = Bbase0 + (size_t)(h) * 128 * DIMF + (T) * 64;      \
    gld_lds16(_gb, _lb + (wid * 16) * 64);                                         \
    gld_lds16(_gb + (size_t)8 * DIMF, _lb + (wid * 16 + 8) * 64);                  \
  } while (0)

  // prologue: T0 complete + T1's tops (order defines the FIFO wait arithmetic)
  STAGE_A(0, 0); STAGE_B(0, 0); STAGE_B(0, 1); STAGE_A(0, 1);
  STAGE_A(1, 0); STAGE_B(1, 0);

  bf16x8 af[4][2], bfr[2][2];

  for (int T = 0; T < 12; ++T) {
    const int dbuf = T & 1;
#pragma unroll
    for (int q = 0; q < 4; ++q) {
      const int ah = q >> 1, bh = q & 1;
      if (q == 0) {
        if (T < 11) asm volatile("s_waitcnt vmcnt(8)" ::: "memory");
        else        asm volatile("s_waitcnt vmcnt(4)" ::: "memory");
      } else if (q == 1) {
        if (T < 11) asm volatile("s_waitcnt vmcnt(8)" ::: "memory");
        else        asm volatile("s_waitcnt vmcnt(2)" ::: "memory");
      } else if (q == 2) {
        if (T < 11) asm volatile("s_waitcnt vmcnt(8)" ::: "memory");
        else        asm volatile("s_waitcnt vmcnt(0)" ::: "memory");
      }
      asm volatile("" ::: "memory");
      __builtin_amdgcn_s_barrier();     // all waves' needed loads visible
      asm volatile("" ::: "memory");

      const unsigned short* Ab = smem + (dbuf * 2 + ah) * 8192;
      const unsigned short* Bb = smem + 32768 + (dbuf * 2 + bh) * 8192;
      if ((q & 1) == 0) {              // A-half frags reused across 2 phases
#pragma unroll
        for (int mp = 0; mp < 4; ++mp)
#pragma unroll
          for (int kk = 0; kk < 2; ++kk) {
            int row = mp * 32 + wr * 16 + lc;
            af[mp][kk] = *(const bf16x8*)&Ab[row * 64 + (((kk * 4 + g) ^ (row & 7)) << 3)];
          }
      }
#pragma unroll
      for (int np = 0; np < 2; ++np)
#pragma unroll
        for (int kk = 0; kk < 2; ++kk) {
          int row = np * 64 + wc * 16 + lc;
          bfr[np][kk] = *(const bf16x8*)&Bb[row * 64 + (((kk * 4 + g) ^ (row & 7)) << 3)];
        }
      // stage issue (slot's readers retired before this phase's barrier):
      if (q == 0)      { if (T + 1 < 12) STAGE_B(T + 1, 1); }   // T+1:B-bot
      else if (q == 1) { if (T + 1 < 12) STAGE_A(T + 1, 1); }   // T+1:A-bot
      else if (q == 2) { if (T + 2 < 12) STAGE_A(T + 2, 0); }   // T+2:A-top
      else             { if (T + 2 < 12) STAGE_B(T + 2, 0); }   // T+2:B-top
      asm volatile("s_waitcnt lgkmcnt(0)" ::: "memory");
      __builtin_amdgcn_sched_barrier(0);   // rule #18
      __builtin_amdgcn_s_setprio(1);
#pragma unroll
      for (int mp = 0; mp < 4; ++mp)
#pragma unroll
        for (int np = 0; np < 2; ++np)
#pragma unroll
          for (int kk = 0; kk < 2; ++kk)
            acc[4 * ah + mp][2 * bh + np] = __builtin_amdgcn_mfma_f32_16x16x32_bf16(
                af[mp][kk], bfr[np][kk], acc[4 * ah + mp][2 * bh + np], 0, 0, 0);
      __builtin_amdgcn_s_setprio(0);
    }
  }
#undef STAGE_A
#undef STAGE_B

  // ---- epilogue (C/D: col=lc, row=g*4+r — proven); block-uniform branch ----
  if (colBase < 768) {   // K output + rope (rope slice staged in now-free LDS)
    float* smemf = (float*)smem;        // 256 rows x 128 f32 = 128KB (exact fit)
    const int nkvBase = rowBase & 4095; // row-within-batch; tile never crosses batch
    lds_barrier();                      // all waves done with dbuf reads
#pragma unroll
    for (int i = 0; i < 16; ++i) {
      int idx4 = t + i * 512;           // 0..8191 float4 slots
      f32x4 v = *(const f32x4*)(rope + (size_t)nkvBase * 128 + (size_t)idx4 * 4);
      *(f32x4*)&smemf[idx4 * 4] = v;
    }
    lds_barrier();                      // rope slice visible
#pragma unroll
    for (int m = 0; m < 8; ++m)
#pragma unroll
      for (int n = 0; n < 4; ++n)
#pragma unroll
        for (int r = 0; r < 4; ++r) {
          int p = rowBase + m * 32 + wr * 16 + g * 4 + r;
          int f = colBase + n * 64 + wc * 16 + lc;
          int d = f & 63, h = f >> 6;
          float v = acc[m][n][r];
          float vo = __shfl_xor(v, 1);
          int b = p >> 12, nkv = p & 4095;
          int nl = p - rowBase;
          float sn = smemf[nl * 128 + d], cs = smemf[nl * 128 + 64 + d];
          float o = (d & 1) ? fmaf(vo, sn, v * cs) : fmaf(-vo, sn, v * cs);
          Ko[((size_t)(b * NHEAD + h) * NKV + nkv) * 64 + d] = f2bf(o);
        }
  } else {               // V output, transposed [b][h][d][nkv]
#pragma unroll
    for (int m = 0; m < 8; ++m)
#pragma unroll
      for (int n = 0; n < 4; ++n) {
        int p0 = rowBase + m * 32 + wr * 16 + g * 4;
        int b = p0 >> 12, nkv0 = p0 & 4095;
        int f = (colBase - 768) + n * 64 + wc * 16 + lc;
        int d = f & 63, h = f >> 6;
        us4 wv{f2bf(acc[m][n][0]), f2bf(acc[m][n][1]), f2bf(acc[m][n][2]), f2bf(acc[m][n][3])};
        *(us4*)&Vt[((size_t)(b * NHEAD + h) * 64 + d) * NKV + nkv0] = wv;
      }
  }
}

// ---------------- GEMM (R5/R8-proven reg-staged): Q-proj / O-proj -----------
// MODE 2: Q-proj (+rope_q, *0.125) -> Q [b][h][nq][64] bf16  [2D grid]
// MODE 3: O-proj -> out f32 [p][768]                          [2D grid]
template <int MODE>
__launch_bounds__(256, 2)
__global__ void gemm_kernel(const unsigned short* __restrict__ A,
                            const unsigned short* __restrict__ Bt,
                            void* __restrict__ outp,
                            const float* __restrict__ rope) {
  __shared__ unsigned short As[128 * 64];
  __shared__ unsigned short Bs[128 * 64];
  const int t = threadIdx.x;
  const int lane = t & 63, wid = t >> 6;
  const int g = lane >> 4, lc = lane & 15;
  const int wr = wid >> 1, wc = wid & 1;
  const int rowBase = blockIdx.x * 128, colBase = blockIdx.y * 128;

  const f32x4 z4 = {0.f, 0.f, 0.f, 0.f};
  f32x4 acc[4][4];
#pragma unroll
  for (int m = 0; m < 4; ++m)
#pragma unroll
    for (int n = 0; n < 4; ++n) acc[m][n] = z4;

  const int r0 = t >> 3;
  const int c0 = t & 7;

  bf16x8 ra[4], rbx[4];
#pragma unroll
  for (int pp = 0; pp < 4; ++pp) {
    int row = pp * 32 + r0;
    ra[pp] = *(const bf16x8*)(A + (size_t)(rowBase + row) * DIMF + c0 * 8);
    rbx[pp] = *(const bf16x8*)(Bt + (size_t)(colBase + row) * DIMF + c0 * 8);
  }

  for (int kb = 0; kb < 12; ++kb) {
    __syncthreads();
#pragma unroll
    for (int pp = 0; pp < 4; ++pp) {
      int row = pp * 32 + r0;
      int ph = ((c0 ^ (row & 7)) << 3);
      *(bf16x8*)&As[row * 64 + ph] = ra[pp];
      *(bf16x8*)&Bs[row * 64 + ph] = rbx[pp];
    }
    __syncthreads();
    if (kb + 1 < 12) {
      int kn = (kb + 1) * 64;
#pragma unroll
      for (int pp = 0; pp < 4; ++pp) {
        int row = pp * 32 + r0;
        ra[pp] = *(const bf16x8*)(A + (size_t)(rowBase + row) * DIMF + kn + c0 * 8);
        rbx[pp] = *(const bf16x8*)(Bt + (size_t)(colBase + row) * DIMF + kn + c0 * 8);
      }
    }
#pragma unroll
    for (int kk = 0; kk < 2; ++kk) {
      bf16x8 af[4], bfr[4];
#pragma unroll
      for (int m = 0; m < 4; ++m) {
        int row = wr * 64 + m * 16 + lc;
        int ch = kk * 4 + g;
        af[m] = *(const bf16x8*)&As[row * 64 + (((ch ^ (row & 7))) << 3)];
      }
#pragma unroll
      for (int n = 0; n < 4; ++n) {
        int row = wc * 64 + n * 16 + lc;
        int ch = kk * 4 + g;
        bfr[n] = *(const bf16x8*)&Bs[row * 64 + (((ch ^ (row & 7))) << 3)];
      }
#pragma unroll
      for (int m = 0; m < 4; ++m)
#pragma unroll
        for (int n = 0; n < 4; ++n)
          acc[m][n] = __builtin_amdgcn_mfma_f32_16x16x32_bf16(af[m], bfr[n], acc[m][n], 0, 0, 0);
    }
  }

  if (MODE == 2) {
    unsigned short* Ko = (unsigned short*)outp;
#pragma unroll
    for (int m = 0; m < 4; ++m)
#pragma unroll
      for (int n = 0; n < 4; ++n)
#pragma unroll
        for (int r = 0; r < 4; ++r) {
          int p = rowBase + wr * 64 + m * 16 + g * 4 + r;
          int f = colBase + wc * 64 + n * 16 + lc;
          int d = f & 63, h = f >> 6;
          float v = acc[m][n][r];
          float vo = __shfl_xor(v, 1);
          int b = p >> 8, nq = p & 255;
          float sn = rope[nq * 128 + d], cs = rope[nq * 128 + 64 + d];
          float o = (d & 1) ? fmaf(vo, sn, v * cs) : fmaf(-vo, sn, v * cs);
          Ko[((size_t)(b * NHEAD + h) * NQ + nq) * 64 + d] = f2bf(o * 0.125f);
        }
  } else {
    float* Co = (float*)outp;
#pragma unroll
    for (int m = 0; m < 4; ++m)
#pragma unroll
      for (int n = 0; n < 4; ++n)
#pragma unroll
        for (int r = 0; r < 4; ++r) {
          int p = rowBase + wr * 64 + m * 16 + g * 4 + r;
          int f = colBase + wc * 64 + n * 16 + lc;
          Co[(size_t)p * DIMF + f] = acc[m][n][r];
        }
  }
}

// ---------------- flash attention (R22-proven, verbatim) --------------------
__launch_bounds__(256, 3)
__global__ void attn_kernel(const unsigned short* __restrict__ Qb,
                            const unsigned short* __restrict__ Kb,
                            const unsigned short* __restrict__ Vtb,
                            unsigned short* __restrict__ Ob) {
  __shared__ unsigned short Ks[128 * 64];    // [kv][d]  16KB, chunk ^= (kv&7)
  __shared__ unsigned short Vts[64 * 128];   // [d][kv'] 16KB, chunk ^= (d&15)
  const int logical = (blockIdx.x & 7) * 96 + (blockIdx.x >> 3);  // 768%8==0
  const int qt = logical & 3, bh = logical >> 2;
  const int b = bh / NHEAD, h = bh % NHEAD;
  const int t = threadIdx.x;
  const int lane = t & 63, w = t >> 6;
  const int g = lane >> 4, lc = lane & 15;
  const int qrow = qt * 64 + w * 16 + lc;

  bf16x8 qf[2];
#pragma unroll
  for (int kk = 0; kk < 2; ++kk)
    qf[kk] = *(const bf16x8*)(Qb + ((size_t)bh * NQ + qrow) * 64 + kk * 32 + g * 8);

  const f32x4 z4 = {0.f, 0.f, 0.f, 0.f};
  f32x4 oacc[4];
#pragma unroll
  for (int df = 0; df < 4; ++df) oacc[df] = z4;
  float mrun = -1e30f, lrun = 0.f;

  const int r0 = t >> 3, c0 = t & 7;
  const int d0 = t >> 4, cv = t & 15;
  const int pbase = 32 * (cv >> 2) + 16 * (cv & 1) + 4 * ((cv >> 1) & 1);
  const int ch0 = pbase >> 3, of0 = pbase & 7;
  const int ch1 = (pbase + 8) >> 3;

  u16x8 rk[4], rv[4];
#define LOAD_TILE(KT)                                                                        \
  do {                                                                                       \
    const int kvb = (KT) * 128;                                                              \
    _Pragma("unroll")                                                                        \
    for (int pp = 0; pp < 4; ++pp)                                                           \
      rk[pp] = *(const u16x8*)(Kb + ((size_t)bh * NKV + kvb + pp * 32 + r0) * 64 + c0 * 8);  \
    _Pragma("unroll")                                                                        \
    for (int pp = 0; pp < 4; ++pp)                                                           \
      rv[pp] = *(const u16x8*)(Vtb + ((size_t)bh * 64 + pp * 16 + d0) * NKV + kvb + cv * 8); \
  } while (0)

  LOAD_TILE(0);

  for (int kt = 0; kt < 32; ++kt) {
    lds_barrier();   // prev tile's LDS reads done (lgkm only — no vmcnt drain)
#pragma unroll
    for (int pp = 0; pp < 4; ++pp) {
      int row = pp * 32 + r0;
      *(u16x8*)&Ks[row * 64 + ((c0 ^ (row & 7)) << 3)] = rk[pp];
    }
#pragma unroll
    for (int pp = 0; pp < 4; ++pp) {
      int d = pp * 16 + d0;
      u16x4 lo = __builtin_shufflevector(rv[pp], rv[pp], 0, 1, 2, 3);
      u16x4 hi = __builtin_shufflevector(rv[pp], rv[pp], 4, 5, 6, 7);
      *(u16x4*)&Vts[d * 128 + ((ch0 ^ (d & 15)) << 3) + of0] = lo;
      *(u16x4*)&Vts[d * 128 + ((ch1 ^ (d & 15)) << 3) + of0] = hi;
    }
    if (kt + 1 < 32) LOAD_TILE(kt + 1);   // prefetch; stays in flight across barrier
    lds_barrier();   // staging visible (lgkm only — prefetch NOT drained)

    f32x4 s[8];
#pragma unroll
    for (int c = 0; c < 8; ++c) s[c] = z4;
    __builtin_amdgcn_s_setprio(1);   // T5: favor matrix pipe during QK^T
#pragma unroll
    for (int kk = 0; kk < 2; ++kk)
#pragma unroll
      for (int c = 0; c < 8; ++c) {
        int row = c * 16 + lc;
        bf16x8 kf = *(const bf16x8*)&Ks[row * 64 + (((kk * 4 + g) ^ (row & 7)) << 3)];
        s[c] = __builtin_amdgcn_mfma_f32_16x16x32_bf16(kf, qf[kk], s[c], 0, 0, 0);
      }
    __builtin_amdgcn_s_setprio(0);

    float mx = s[0][0];
#pragma unroll
    for (int c = 0; c < 8; ++c)
#pragma unroll
      for (int r = 0; r < 4; ++r) mx = fmaxf(mx, s[c][r]);
    mx = fmaxf(mx, __shfl_xor(mx, 16));
    mx = fmaxf(mx, __shfl_xor(mx, 32));
    // T13 defer-max: skip rescale when max growth <= 8 (P bounded by e^8)
    if (!__all(mx - mrun <= 8.f)) {
      float nm = fmaxf(mrun, mx);
      float al = __expf(mrun - nm);
      mrun = nm;
      lrun *= al;
#pragma unroll
      for (int df = 0; df < 4; ++df)
#pragma unroll
        for (int r = 0; r < 4; ++r) oacc[df][r] *= al;
    }
    float ls = 0.f;
#pragma unroll
    for (int c = 0; c < 8; ++c)
#pragma unroll
      for (int r = 0; r < 4; ++r) {
        float p = __expf(s[c][r] - mrun);
        s[c][r] = p;
        ls += p;
      }
    ls += __shfl_xor(ls, 16);
    ls += __shfl_xor(ls, 32);
    lrun += ls;

    uint32_t pk[8][2];
#pragma unroll
    for (int c = 0; c < 8; ++c)
#pragma unroll
      for (int w2 = 0; w2 < 2; ++w2)
        pk[c][w2] = cvtpk(s[c][2 * w2], s[c][2 * w2 + 1]);

    __builtin_amdgcn_s_setprio(1);   // T5: favor matrix pipe during PV
#pragma unroll
    for (int kb = 0; kb < 4; ++kb) {
      u32x4 pw = {pk[2 * kb][0], pk[2 * kb][1], pk[2 * kb + 1][0], pk[2 * kb + 1][1]};
      bf16x8 pa = __builtin_bit_cast(bf16x8, pw);
#pragma unroll
      for (int df = 0; df < 4; ++df) {
        int row = df * 16 + lc;
        bf16x8 vf = *(const bf16x8*)&Vts[row * 128 + (((kb * 4 + g) ^ (row & 15)) << 3)];
        oacc[df] = __builtin_amdgcn_mfma_f32_16x16x32_bf16(vf, pa, oacc[df], 0, 0, 0);
      }
    }
    __builtin_amdgcn_s_setprio(0);
  }
#undef LOAD_TILE

  float inv = 1.0f / lrun;
#pragma unroll
  for (int df = 0; df < 4; ++df) {
    us4 wv{f2bf(oacc[df][0] * inv), f2bf(oacc[df][1] * inv),
           f2bf(oacc[df][2] * inv), f2bf(oacc[df][3] * inv)};
    *(us4*)&Ob[((size_t)b * NQ + qrow) * DIMF + h * 64 + df * 16 + g * 4] = wv;
  }
}

// ---------------- launch ----------------------------------------------------
extern "C" void kernel_launch(void* const* d_in, const int* in_sizes, int n_in,
                              void* d_out, int out_size, void* d_ws, size_t ws_size,
                              hipStream_t stream) {
  const float* x      = (const float*)d_in[0];
  const float* ctx    = (const float*)d_in[1];
  const float* rope_q = (const float*)d_in[2];
  const float* rope_k = (const float*)d_in[3];
  const float* Wq     = (const float*)d_in[4];
  const float* Wk     = (const float*)d_in[5];
  const float* Wv     = (const float*)d_in[6];
  const float* Wo     = (const float*)d_in[7];

  char* ws = (char*)d_ws;
  const size_t SZ_CTXB = (size_t)NB * NKV * DIMF * 2;
  const size_t SZ_XB   = (size_t)NB * NQ * DIMF * 2;
  const size_t SZ_WT   = (size_t)DIMF * DIMF * 2;
  unsigned short* ctxb = (unsigned short*)(ws);
  unsigned short* ob   = (unsigned short*)(ws);                       // alias ctxb (dead after kvgemm)
  unsigned short* xb   = (unsigned short*)(ws + SZ_CTXB);
  unsigned short* wkt  = (unsigned short*)(ws + SZ_CTXB + SZ_XB);           // wkt||wvt = wkvt[1536][768]
  unsigned short* wvt  = (unsigned short*)(ws + SZ_CTXB + SZ_XB + SZ_WT);
  unsigned short* wqt  = (unsigned short*)(ws + SZ_CTXB + SZ_XB + 2 * SZ_WT);
  unsigned short* wot  = (unsigned short*)(ws + SZ_CTXB + SZ_XB + 3 * SZ_WT);
  unsigned short* kb   = (unsigned short*)(ws + SZ_CTXB + SZ_XB + 4 * SZ_WT);
  unsigned short* vtb  = (unsigned short*)(ws + SZ_CTXB + SZ_XB + 4 * SZ_WT + SZ_CTXB);
  unsigned short* qb   = (unsigned short*)(ws + SZ_CTXB + SZ_XB + 4 * SZ_WT + 2 * SZ_CTXB);

  cvt_kernel<<<dim3(2048), dim3(256), 0, stream>>>(ctx, ctxb, NB * NKV * DIMF);
  cvt_kernel<<<dim3(1024), dim3(256), 0, stream>>>(x, xb, NB * NQ * DIMF);
  twt_kernel<<<dim3(24, 24, 4), dim3(32, 8), 0, stream>>>(Wk, Wv, Wq, Wo, wkt, wvt, wqt, wot);

  kv8_kernel<<<dim3(1536), dim3(512), 131072, stream>>>(ctxb, wkt, kb, vtb, rope_k);
  gemm_kernel<2><<<dim3(32, 6), dim3(256), 0, stream>>>(xb, wqt, qb, rope_q);

  attn_kernel<<<dim3(768), dim3(256), 0, stream>>>(qb, kb, vtb, ob);

  gemm_kernel<3><<<dim3(32, 6), dim3(256), 0, stream>>>(ob, wot, d_out, nullptr);
}

// Round 25
// 363.342 us; speedup vs baseline: 1.1108x; 1.0079x over previous
//
#include <hip/hip_runtime.h>
#include <stdint.h>

// ---------------------------------------------------------------------------
// CrossAttentionRope: x(16,256,768), ctx(16,4096,768) f32 -> out(16,256,768) f32
// R25: R24 (best, 366.2us) + V-epilogue LDS transpose staging: the 32 scattered
//      8B stores/thread (lane stride 8KB) become a 128KB staged [f][nkv] tile
//      (exact smem fit; V branch never uses the rope slice) + fully-coalesced
//      16B stores along nkv. Pair-preserving even-XOR (chunk ^ ((f&31)<<1))
//      keeps LDS writes/reads conflict-light. Everything else verbatim R24.
// ---------------------------------------------------------------------------

typedef __bf16 bf16x8 __attribute__((ext_vector_type(8)));
typedef unsigned short u16x8 __attribute__((ext_vector_type(8)));
typedef unsigned short u16x4 __attribute__((ext_vector_type(4)));
typedef uint32_t u32x4 __attribute__((ext_vector_type(4)));
typedef float f32x4 __attribute__((ext_vector_type(4)));

#define DIMF 768
#define NHEAD 12
#define NKV 4096
#define NQ 256
#define NB 16

struct alignas(8) us4 { unsigned short x, y, z, w; };

__device__ __forceinline__ unsigned short f2bf(float x) {
  uint32_t u = __float_as_uint(x);
  u += 0x7fffu + ((u >> 16) & 1u);   // round-to-nearest-even
  return (unsigned short)(u >> 16);
}

__device__ __forceinline__ uint32_t cvtpk(float a, float b) {
  uint32_t r;
  asm("v_cvt_pk_bf16_f32 %0, %1, %2" : "=v"(r) : "v"(a), "v"(b));
  return r;
}

__device__ __forceinline__ void gld_lds16(const unsigned short* g, unsigned short* l) {
  __builtin_amdgcn_global_load_lds(
      (const __attribute__((address_space(1))) uint32_t*)(uintptr_t)g,
      (__attribute__((address_space(3))) uint32_t*)(uintptr_t)l, 16, 0, 0);
}

// lgkm-only barrier (no vmcnt drain): per-wave LDS ops complete, then sync.
__device__ __forceinline__ void lds_barrier() {
  asm volatile("s_waitcnt lgkmcnt(0)" ::: "memory");
  asm volatile("" ::: "memory");
  __builtin_amdgcn_s_barrier();
  asm volatile("" ::: "memory");
}

// ---------------- convert f32 -> bf16 (vectorized, grid-stride) ------------
__global__ void cvt_kernel(const float* __restrict__ in, unsigned short* __restrict__ out, int n) {
  int stride = gridDim.x * blockDim.x * 4;
  for (int i = (blockIdx.x * blockDim.x + threadIdx.x) * 4; i < n; i += stride) {
    float4 v = *(const float4*)(in + i);
    us4 o{f2bf(v.x), f2bf(v.y), f2bf(v.z), f2bf(v.w)};
    *(us4*)(out + i) = o;
  }
}

// ---------------- weight transpose + cvt: Wt[n][k] = W[k][n] ---------------
__global__ void twt_kernel(const float* __restrict__ W0, const float* __restrict__ W1,
                           const float* __restrict__ W2, const float* __restrict__ W3,
                           unsigned short* __restrict__ O0, unsigned short* __restrict__ O1,
                           unsigned short* __restrict__ O2, unsigned short* __restrict__ O3) {
  const float* W; unsigned short* O;
  switch (blockIdx.z) {
    case 0: W = W0; O = O0; break;
    case 1: W = W1; O = O1; break;
    case 2: W = W2; O = O2; break;
    default: W = W3; O = O3; break;
  }
  __shared__ float t[32][33];
  int x0 = blockIdx.x * 32, y0 = blockIdx.y * 32;
  int tx = threadIdx.x, ty = threadIdx.y;
#pragma unroll
  for (int j = 0; j < 4; ++j)
    t[ty + 8 * j][tx] = W[(size_t)(y0 + ty + 8 * j) * DIMF + x0 + tx];
  __syncthreads();
#pragma unroll
  for (int j = 0; j < 4; ++j)
    O[(size_t)(x0 + ty + 8 * j) * DIMF + y0 + tx] = f2bf(t[tx][ty + 8 * j]);
}

// ---------------- merged KV GEMM: 256x256, 8-phase per-phase-vmcnt ----------
// (R17-proven.) Grid 1536 (256 rows x 6 cols), col-fast XCD swizzle.
// 512 thr / 8 waves; per-wave C = 128x64 interleaved.
__launch_bounds__(512, 1)
__global__ void kv8_kernel(const unsigned short* __restrict__ A,
                           const unsigned short* __restrict__ Bkv,
                           unsigned short* __restrict__ Ko,
                           unsigned short* __restrict__ Vt,
                           const float* __restrict__ rope) {
  extern __shared__ unsigned short smem[];   // 65536 shorts = 128KB
  const int t = threadIdx.x;
  const int lane = t & 63, wid = t >> 6;
  const int g = lane >> 4, lc = lane & 15;
  const int wr = wid >> 2, wc = wid & 3;

  const int swz = (blockIdx.x & 7) * 192 + (blockIdx.x >> 3);  // 1536%8==0
  const int rowBase = (swz / 6) * 256;
  const int colBase = (swz % 6) * 256;

  f32x4 acc[8][4];
#pragma unroll
  for (int m = 0; m < 8; ++m)
#pragma unroll
    for (int n = 0; n < 4; ++n)
#pragma unroll
      for (int r = 0; r < 4; ++r) acc[m][n][r] = 0.f;

  const int sr = lane >> 3;
  const int sc = (lane & 7) ^ sr;
  const unsigned short* Abase0 = A + (size_t)(rowBase + wid * 16 + sr) * DIMF + sc * 8;
  const unsigned short* Bbase0 = Bkv + (size_t)(colBase + wid * 16 + sr) * DIMF + sc * 8;

#define STAGE_A(T, h)                                                              \
  do {                                                                             \
    unsigned short* _lb = smem + (((T) & 1) * 2 + (h)) * 8192;                     \
    const unsigned short* _gb = Abase0 + (size_t)(h) * 128 * DIMF + (T) * 64;      \
    gld_lds16(_gb, _lb + (wid * 16) * 64);                                         \
    gld_lds16(_gb + (size_t)8 * DIMF, _lb + (wid * 16 + 8) * 64);                  \
  } while (0)
#define STAGE_B(T, h)                                                              \
  do {                                                                             \
    unsigned short* _lb = smem + 32768 + (((T) & 1) * 2 + (h)) * 8192;             \
    const unsigned short* _gb = Bbase0 + (size_t)(h) * 128 * DIMF + (T) * 64;      \
    gld_lds16(_gb, _lb + (wid * 16) * 64);                                         \
    gld_lds16(_gb + (size_t)8 * DIMF, _lb + (wid * 16 + 8) * 64);                  \
  } while (0)

  // prologue: T0 complete + T1's tops (order defines the FIFO wait arithmetic)
  STAGE_A(0, 0); STAGE_B(0, 0); STAGE_B(0, 1); STAGE_A(0, 1);
  STAGE_A(1, 0); STAGE_B(1, 0);

  bf16x8 af[4][2], bfr[2][2];

  for (int T = 0; T < 12; ++T) {
    const int dbuf = T & 1;
#pragma unroll
    for (int q = 0; q < 4; ++q) {
      const int ah = q >> 1, bh = q & 1;
      if (q == 0) {
        if (T < 11) asm volatile("s_waitcnt vmcnt(8)" ::: "memory");
        else        asm volatile("s_waitcnt vmcnt(4)" ::: "memory");
      } else if (q == 1) {
        if (T < 11) asm volatile("s_waitcnt vmcnt(8)" ::: "memory");
        else        asm volatile("s_waitcnt vmcnt(2)" ::: "memory");
      } else if (q == 2) {
        if (T < 11) asm volatile("s_waitcnt vmcnt(8)" ::: "memory");
        else        asm volatile("s_waitcnt vmcnt(0)" ::: "memory");
      }
      asm volatile("" ::: "memory");
      __builtin_amdgcn_s_barrier();     // all waves' needed loads visible
      asm volatile("" ::: "memory");

      const unsigned short* Ab = smem + (dbuf * 2 + ah) * 8192;
      const unsigned short* Bb = smem + 32768 + (dbuf * 2 + bh) * 8192;
      if ((q & 1) == 0) {              // A-half frags reused across 2 phases
#pragma unroll
        for (int mp = 0; mp < 4; ++mp)
#pragma unroll
          for (int kk = 0; kk < 2; ++kk) {
            int row = mp * 32 + wr * 16 + lc;
            af[mp][kk] = *(const bf16x8*)&Ab[row * 64 + (((kk * 4 + g) ^ (row & 7)) << 3)];
          }
      }
#pragma unroll
      for (int np = 0; np < 2; ++np)
#pragma unroll
        for (int kk = 0; kk < 2; ++kk) {
          int row = np * 64 + wc * 16 + lc;
          bfr[np][kk] = *(const bf16x8*)&Bb[row * 64 + (((kk * 4 + g) ^ (row & 7)) << 3)];
        }
      // stage issue (slot's readers retired before this phase's barrier):
      if (q == 0)      { if (T + 1 < 12) STAGE_B(T + 1, 1); }   // T+1:B-bot
      else if (q == 1) { if (T + 1 < 12) STAGE_A(T + 1, 1); }   // T+1:A-bot
      else if (q == 2) { if (T + 2 < 12) STAGE_A(T + 2, 0); }   // T+2:A-top
      else             { if (T + 2 < 12) STAGE_B(T + 2, 0); }   // T+2:B-top
      asm volatile("s_waitcnt lgkmcnt(0)" ::: "memory");
      __builtin_amdgcn_sched_barrier(0);   // rule #18
      __builtin_amdgcn_s_setprio(1);
#pragma unroll
      for (int mp = 0; mp < 4; ++mp)
#pragma unroll
        for (int np = 0; np < 2; ++np)
#pragma unroll
          for (int kk = 0; kk < 2; ++kk)
            acc[4 * ah + mp][2 * bh + np] = __builtin_amdgcn_mfma_f32_16x16x32_bf16(
                af[mp][kk], bfr[np][kk], acc[4 * ah + mp][2 * bh + np], 0, 0, 0);
      __builtin_amdgcn_s_setprio(0);
    }
  }
#undef STAGE_A
#undef STAGE_B

  // ---- epilogue (C/D: col=lc, row=g*4+r — proven); block-uniform branch ----
  if (colBase < 768) {   // K output + rope (rope slice staged in now-free LDS)
    float* smemf = (float*)smem;        // 256 rows x 128 f32 = 128KB (exact fit)
    const int nkvBase = rowBase & 4095; // row-within-batch; tile never crosses batch
    lds_barrier();                      // all waves done with dbuf reads
#pragma unroll
    for (int i = 0; i < 16; ++i) {
      int idx4 = t + i * 512;           // 0..8191 float4 slots
      f32x4 v = *(const f32x4*)(rope + (size_t)nkvBase * 128 + (size_t)idx4 * 4);
      *(f32x4*)&smemf[idx4 * 4] = v;
    }
    lds_barrier();                      // rope slice visible
#pragma unroll
    for (int m = 0; m < 8; ++m)
#pragma unroll
      for (int n = 0; n < 4; ++n)
#pragma unroll
        for (int r = 0; r < 4; ++r) {
          int p = rowBase + m * 32 + wr * 16 + g * 4 + r;
          int f = colBase + n * 64 + wc * 16 + lc;
          int d = f & 63, h = f >> 6;
          float v = acc[m][n][r];
          float vo = __shfl_xor(v, 1);
          int b = p >> 12, nkv = p & 4095;
          int nl = p - rowBase;
          float sn = smemf[nl * 128 + d], cs = smemf[nl * 128 + 64 + d];
          float o = (d & 1) ? fmaf(vo, sn, v * cs) : fmaf(-vo, sn, v * cs);
          Ko[((size_t)(b * NHEAD + h) * NKV + nkv) * 64 + d] = f2bf(o);
        }
  } else {               // V output staged via LDS transpose -> coalesced 16B stores
    unsigned short* smv = smem;         // [f_local][nkv chunks swizzled] 128KB exact
    lds_barrier();                      // all waves done with dbuf reads
#pragma unroll
    for (int m = 0; m < 8; ++m)
#pragma unroll
      for (int n = 0; n < 4; ++n) {
        int fl = n * 64 + wc * 16 + lc;          // 0..255
        int c = (m * 32 + wr * 16 + g * 4) >> 2; // 8B chunk 0..63 (nk0 mult of 4)
        int pc = c ^ (((fl & 31) << 1) & 63);    // even XOR: pairs preserved
        us4 wv{f2bf(acc[m][n][0]), f2bf(acc[m][n][1]), f2bf(acc[m][n][2]), f2bf(acc[m][n][3])};
        *(us4*)&smv[fl * 256 + pc * 4] = wv;
      }
    lds_barrier();                      // staged tile visible
    {
      int fl = t >> 1, half = t & 1;    // row (0..255), 128-nkv half
      int fg = (colBase - 768) + fl;
      int d = fg & 63, h = fg >> 6;
      int b = rowBase >> 12;
      int nkvb = (rowBase & 4095) + half * 128;
      unsigned short* dst = Vt + ((size_t)(b * NHEAD + h) * 64 + d) * NKV + nkvb;
      int v = ((fl & 31) << 1) & 63;
#pragma unroll
      for (int j = 0; j < 16; ++j) {
        int c = half * 32 + j * 2;      // even chunk index
        int pc = c ^ v;                 // even -> 16B-aligned, pair contiguous
        u16x8 val = *(const u16x8*)&smv[fl * 256 + pc * 4];
        *(u16x8*)(dst + j * 8) = val;
      }
    }
  }
}

// ---------------- GEMM (R5/R8-proven reg-staged): Q-proj / O-proj -----------
// MODE 2: Q-proj (+rope_q, *0.125) -> Q [b][h][nq][64] bf16  [2D grid]
// MODE 3: O-proj -> out f32 [p][768]                          [2D grid]
template <int MODE>
__launch_bounds__(256, 2)
__global__ void gemm_kernel(const unsigned short* __restrict__ A,
                            const unsigned short* __restrict__ Bt,
                            void* __restrict__ outp,
                            const float* __restrict__ rope) {
  __shared__ unsigned short As[128 * 64];
  __shared__ unsigned short Bs[128 * 64];
  const int t = threadIdx.x;
  const int lane = t & 63, wid = t >> 6;
  const int g = lane >> 4, lc = lane & 15;
  const int wr = wid >> 1, wc = wid & 1;
  const int rowBase = blockIdx.x * 128, colBase = blockIdx.y * 128;

  const f32x4 z4 = {0.f, 0.f, 0.f, 0.f};
  f32x4 acc[4][4];
#pragma unroll
  for (int m = 0; m < 4; ++m)
#pragma unroll
    for (int n = 0; n < 4; ++n) acc[m][n] = z4;

  const int r0 = t >> 3;
  const int c0 = t & 7;

  bf16x8 ra[4], rbx[4];
#pragma unroll
  for (int pp = 0; pp < 4; ++pp) {
    int row = pp * 32 + r0;
    ra[pp] = *(const bf16x8*)(A + (size_t)(rowBase + row) * DIMF + c0 * 8);
    rbx[pp] = *(const bf16x8*)(Bt + (size_t)(colBase + row) * DIMF + c0 * 8);
  }

  for (int kb = 0; kb < 12; ++kb) {
    __syncthreads();
#pragma unroll
    for (int pp = 0; pp < 4; ++pp) {
      int row = pp * 32 + r0;
      int ph = ((c0 ^ (row & 7)) << 3);
      *(bf16x8*)&As[row * 64 + ph] = ra[pp];
      *(bf16x8*)&Bs[row * 64 + ph] = rbx[pp];
    }
    __syncthreads();
    if (kb + 1 < 12) {
      int kn = (kb + 1) * 64;
#pragma unroll
      for (int pp = 0; pp < 4; ++pp) {
        int row = pp * 32 + r0;
        ra[pp] = *(const bf16x8*)(A + (size_t)(rowBase + row) * DIMF + kn + c0 * 8);
        rbx[pp] = *(const bf16x8*)(Bt + (size_t)(colBase + row) * DIMF + kn + c0 * 8);
      }
    }
#pragma unroll
    for (int kk = 0; kk < 2; ++kk) {
      bf16x8 af[4], bfr[4];
#pragma unroll
      for (int m = 0; m < 4; ++m) {
        int row = wr * 64 + m * 16 + lc;
        int ch = kk * 4 + g;
        af[m] = *(const bf16x8*)&As[row * 64 + (((ch ^ (row & 7))) << 3)];
      }
#pragma unroll
      for (int n = 0; n < 4; ++n) {
        int row = wc * 64 + n * 16 + lc;
        int ch = kk * 4 + g;
        bfr[n] = *(const bf16x8*)&Bs[row * 64 + (((ch ^ (row & 7))) << 3)];
      }
#pragma unroll
      for (int m = 0; m < 4; ++m)
#pragma unroll
        for (int n = 0; n < 4; ++n)
          acc[m][n] = __builtin_amdgcn_mfma_f32_16x16x32_bf16(af[m], bfr[n], acc[m][n], 0, 0, 0);
    }
  }

  if (MODE == 2) {
    unsigned short* Ko = (unsigned short*)outp;
#pragma unroll
    for (int m = 0; m < 4; ++m)
#pragma unroll
      for (int n = 0; n < 4; ++n)
#pragma unroll
        for (int r = 0; r < 4; ++r) {
          int p = rowBase + wr * 64 + m * 16 + g * 4 + r;
          int f = colBase + wc * 64 + n * 16 + lc;
          int d = f & 63, h = f >> 6;
          float v = acc[m][n][r];
          float vo = __shfl_xor(v, 1);
          int b = p >> 8, nq = p & 255;
          float sn = rope[nq * 128 + d], cs = rope[nq * 128 + 64 + d];
          float o = (d & 1) ? fmaf(vo, sn, v * cs) : fmaf(-vo, sn, v * cs);
          Ko[((size_t)(b * NHEAD + h) * NQ + nq) * 64 + d] = f2bf(o * 0.125f);
        }
  } else {
    float* Co = (float*)outp;
#pragma unroll
    for (int m = 0; m < 4; ++m)
#pragma unroll
      for (int n = 0; n < 4; ++n)
#pragma unroll
        for (int r = 0; r < 4; ++r) {
          int p = rowBase + wr * 64 + m * 16 + g * 4 + r;
          int f = colBase + wc * 64 + n * 16 + lc;
          Co[(size_t)p * DIMF + f] = acc[m][n][r];
        }
  }
}

// ---------------- flash attention (R22-proven, verbatim) --------------------
__launch_bounds__(256, 3)
__global__ void attn_kernel(const unsigned short* __restrict__ Qb,
                            const unsigned short* __restrict__ Kb,
                            const unsigned short* __restrict__ Vtb,
                            unsigned short* __restrict__ Ob) {
  __shared__ unsigned short Ks[128 * 64];    // [kv][d]  16KB, chunk ^= (kv&7)
  __shared__ unsigned short Vts[64 * 128];   // [d][kv'] 16KB, chunk ^= (d&15)
  const int logical = (blockIdx.x & 7) * 96 + (blockIdx.x >> 3);  // 768%8==0
  const int qt = logical & 3, bh = logical >> 2;
  const int b = bh / NHEAD, h = bh % NHEAD;
  const int t = threadIdx.x;
  const int lane = t & 63, w = t >> 6;
  const int g = lane >> 4, lc = lane & 15;
  const int qrow = qt * 64 + w * 16 + lc;

  bf16x8 qf[2];
#pragma unroll
  for (int kk = 0; kk < 2; ++kk)
    qf[kk] = *(const bf16x8*)(Qb + ((size_t)bh * NQ + qrow) * 64 + kk * 32 + g * 8);

  const f32x4 z4 = {0.f, 0.f, 0.f, 0.f};
  f32x4 oacc[4];
#pragma unroll
  for (int df = 0; df < 4; ++df) oacc[df] = z4;
  float mrun = -1e30f, lrun = 0.f;

  const int r0 = t >> 3, c0 = t & 7;
  const int d0 = t >> 4, cv = t & 15;
  const int pbase = 32 * (cv >> 2) + 16 * (cv & 1) + 4 * ((cv >> 1) & 1);
  const int ch0 = pbase >> 3, of0 = pbase & 7;
  const int ch1 = (pbase + 8) >> 3;

  u16x8 rk[4], rv[4];
#define LOAD_TILE(KT)                                                                        \
  do {                                                                                       \
    const int kvb = (KT) * 128;                                                              \
    _Pragma("unroll")                                                                        \
    for (int pp = 0; pp < 4; ++pp)                                                           \
      rk[pp] = *(const u16x8*)(Kb + ((size_t)bh * NKV + kvb + pp * 32 + r0) * 64 + c0 * 8);  \
    _Pragma("unroll")                                                                        \
    for (int pp = 0; pp < 4; ++pp)                                                           \
      rv[pp] = *(const u16x8*)(Vtb + ((size_t)bh * 64 + pp * 16 + d0) * NKV + kvb + cv * 8); \
  } while (0)

  LOAD_TILE(0);

  for (int kt = 0; kt < 32; ++kt) {
    lds_barrier();   // prev tile's LDS reads done (lgkm only — no vmcnt drain)
#pragma unroll
    for (int pp = 0; pp < 4; ++pp) {
      int row = pp * 32 + r0;
      *(u16x8*)&Ks[row * 64 + ((c0 ^ (row & 7)) << 3)] = rk[pp];
    }
#pragma unroll
    for (int pp = 0; pp < 4; ++pp) {
      int d = pp * 16 + d0;
      u16x4 lo = __builtin_shufflevector(rv[pp], rv[pp], 0, 1, 2, 3);
      u16x4 hi = __builtin_shufflevector(rv[pp], rv[pp], 4, 5, 6, 7);
      *(u16x4*)&Vts[d * 128 + ((ch0 ^ (d & 15)) << 3) + of0] = lo;
      *(u16x4*)&Vts[d * 128 + ((ch1 ^ (d & 15)) << 3) + of0] = hi;
    }
    if (kt + 1 < 32) LOAD_TILE(kt + 1);   // prefetch; stays in flight across barrier
    lds_barrier();   // staging visible (lgkm only — prefetch NOT drained)

    f32x4 s[8];
#pragma unroll
    for (int c = 0; c < 8; ++c) s[c] = z4;
    __builtin_amdgcn_s_setprio(1);   // T5: favor matrix pipe during QK^T
#pragma unroll
    for (int kk = 0; kk < 2; ++kk)
#pragma unroll
      for (int c = 0; c < 8; ++c) {
        int row = c * 16 + lc;
        bf16x8 kf = *(const bf16x8*)&Ks[row * 64 + (((kk * 4 + g) ^ (row & 7)) << 3)];
        s[c] = __builtin_amdgcn_mfma_f32_16x16x32_bf16(kf, qf[kk], s[c], 0, 0, 0);
      }
    __builtin_amdgcn_s_setprio(0);

    float mx = s[0][0];
#pragma unroll
    for (int c = 0; c < 8; ++c)
#pragma unroll
      for (int r = 0; r < 4; ++r) mx = fmaxf(mx, s[c][r]);
    mx = fmaxf(mx, __shfl_xor(mx, 16));
    mx = fmaxf(mx, __shfl_xor(mx, 32));
    // T13 defer-max: skip rescale when max growth <= 8 (P bounded by e^8)
    if (!__all(mx - mrun <= 8.f)) {
      float nm = fmaxf(mrun, mx);
      float al = __expf(mrun - nm);
      mrun = nm;
      lrun *= al;
#pragma unroll
      for (int df = 0; df < 4; ++df)
#pragma unroll
        for (int r = 0; r < 4; ++r) oacc[df][r] *= al;
    }
    float ls = 0.f;
#pragma unroll
    for (int c = 0; c < 8; ++c)
#pragma unroll
      for (int r = 0; r < 4; ++r) {
        float p = __expf(s[c][r] - mrun);
        s[c][r] = p;
        ls += p;
      }
    ls += __shfl_xor(ls, 16);
    ls += __shfl_xor(ls, 32);
    lrun += ls;

    uint32_t pk[8][2];
#pragma unroll
    for (int c = 0; c < 8; ++c)
#pragma unroll
      for (int w2 = 0; w2 < 2; ++w2)
        pk[c][w2] = cvtpk(s[c][2 * w2], s[c][2 * w2 + 1]);

    __builtin_amdgcn_s_setprio(1);   // T5: favor matrix pipe during PV
#pragma unroll
    for (int kb = 0; kb < 4; ++kb) {
      u32x4 pw = {pk[2 * kb][0], pk[2 * kb][1], pk[2 * kb + 1][0], pk[2 * kb + 1][1]};
      bf16x8 pa = __builtin_bit_cast(bf16x8, pw);
#pragma unroll
      for (int df = 0; df < 4; ++df) {
        int row = df * 16 + lc;
        bf16x8 vf = *(const bf16x8*)&Vts[row * 128 + (((kb * 4 + g) ^ (row & 15)) << 3)];
        oacc[df] = __builtin_amdgcn_mfma_f32_16x16x32_bf16(vf, pa, oacc[df], 0, 0, 0);
      }
    }
    __builtin_amdgcn_s_setprio(0);
  }
#undef LOAD_TILE

  float inv = 1.0f / lrun;
#pragma unroll
  for (int df = 0; df < 4; ++df) {
    us4 wv{f2bf(oacc[df][0] * inv), f2bf(oacc[df][1] * inv),
           f2bf(oacc[df][2] * inv), f2bf(oacc[df][3] * inv)};
    *(us4*)&Ob[((size_t)b * NQ + qrow) * DIMF + h * 64 + df * 16 + g * 4] = wv;
  }
}

// ---------------- launch ----------------------------------------------------
extern "C" void kernel_launch(void* const* d_in, const int* in_sizes, int n_in,
                              void* d_out, int out_size, void* d_ws, size_t ws_size,
                              hipStream_t stream) {
  const float* x      = (const float*)d_in[0];
  const float* ctx    = (const float*)d_in[1];
  const float* rope_q = (const float*)d_in[2];
  const float* rope_k = (const float*)d_in[3];
  const float* Wq     = (const float*)d_in[4];
  const float* Wk     = (const float*)d_in[5];
  const float* Wv     = (const float*)d_in[6];
  const float* Wo     = (const float*)d_in[7];

  char* ws = (char*)d_ws;
  const size_t SZ_CTXB = (size_t)NB * NKV * DIMF * 2;
  const size_t SZ_XB   = (size_t)NB * NQ * DIMF * 2;
  const size_t SZ_WT   = (size_t)DIMF * DIMF * 2;
  unsigned short* ctxb = (unsigned short*)(ws);
  unsigned short* ob   = (unsigned short*)(ws);                       // alias ctxb (dead after kvgemm)
  unsigned short* xb   = (unsigned short*)(ws + SZ_CTXB);
  unsigned short* wkt  = (unsigned short*)(ws + SZ_CTXB + SZ_XB);           // wkt||wvt = wkvt[1536][768]
  unsigned short* wvt  = (unsigned short*)(ws + SZ_CTXB + SZ_XB + SZ_WT);
  unsigned short* wqt  = (unsigned short*)(ws + SZ_CTXB + SZ_XB + 2 * SZ_WT);
  unsigned short* wot  = (unsigned short*)(ws + SZ_CTXB + SZ_XB + 3 * SZ_WT);
  unsigned short* kb   = (unsigned short*)(ws + SZ_CTXB + SZ_XB + 4 * SZ_WT);
  unsigned short* vtb  = (unsigned short*)(ws + SZ_CTXB + SZ_XB + 4 * SZ_WT + SZ_CTXB);
  unsigned short* qb   = (unsigned short*)(ws + SZ_CTXB + SZ_XB + 4 * SZ_WT + 2 * SZ_CTXB);

  cvt_kernel<<<dim3(2048), dim3(256), 0, stream>>>(ctx, ctxb, NB * NKV * DIMF);
  cvt_kernel<<<dim3(1024), dim3(256), 0, stream>>>(x, xb, NB * NQ * DIMF);
  twt_kernel<<<dim3(24, 24, 4), dim3(32, 8), 0, stream>>>(Wk, Wv, Wq, Wo, wkt, wvt, wqt, wot);

  kv8_kernel<<<dim3(1536), dim3(512), 131072, stream>>>(ctxb, wkt, kb, vtb, rope_k);
  gemm_kernel<2><<<dim3(32, 6), dim3(256), 0, stream>>>(xb, wqt, qb, rope_q);

  attn_kernel<<<dim3(768), dim3(256), 0, stream>>>(qb, kb, vtb, ob);

  gemm_kernel<3><<<dim3(32, 6), dim3(256), 0, stream>>>(ob, wot, d_out, nullptr);
}